// Round 5
// baseline (815.149 us; speedup 1.0000x reference)
//
#include <hip/hip_runtime.h>

#define NEG_SLOPE 0.2f
#define LN_EPS 1e-5f

typedef float f2 __attribute__((ext_vector_type(2)));

__device__ __forceinline__ f2 sp2(float x){ return (f2){x, x}; }
__device__ __forceinline__ f2 fma2(f2 a, f2 b, f2 c){
#if __has_builtin(__builtin_elementwise_fma)
  return __builtin_elementwise_fma(a, b, c);
#else
  f2 r; r.x = fmaf(a.x, b.x, c.x); r.y = fmaf(a.y, b.y, c.y); return r;
#endif
}
__device__ __forceinline__ f2 max2(f2 a, f2 b){
#if __has_builtin(__builtin_elementwise_max)
  return __builtin_elementwise_max(a, b);
#else
  f2 r; r.x = fmaxf(a.x, b.x); r.y = fmaxf(a.y, b.y); return r;
#endif
}
__device__ __forceinline__ f2 min2(f2 a, f2 b){
#if __has_builtin(__builtin_elementwise_min)
  return __builtin_elementwise_min(a, b);
#else
  f2 r; r.x = fminf(a.x, b.x); r.y = fminf(a.y, b.y); return r;
#endif
}

__device__ __forceinline__ float wsum64(float v){
  #pragma unroll
  for (int o = 32; o >= 1; o >>= 1) v += __shfl_xor(v, o);
  return v;
}
// sum within each 32-lane half (shfl -> ds pipe, off-VALU)
__device__ __forceinline__ float gsum32(float v){
  #pragma unroll
  for (int o = 16; o >= 1; o >>= 1) v += __shfl_xor(v, o);
  return v;
}
__device__ __forceinline__ float rlF(float v, int lane){
  return __int_as_float(__builtin_amdgcn_readlane(__float_as_int(v), lane));
}
__device__ __forceinline__ int rlI(int v, int lane){
  return __builtin_amdgcn_readlane(v, lane);
}

// ---------------- CSR build ----------------
__global__ void k_count(const int* __restrict__ dst, int* __restrict__ deg, int E){
  int e = blockIdx.x * blockDim.x + threadIdx.x;
  if (e < E) atomicAdd(&deg[dst[e]], 1);
}

__global__ void k_scan_blk(const int* __restrict__ deg, int* __restrict__ part,
                           int* __restrict__ sums, int n){
  __shared__ int buf[256];
  int t = threadIdx.x, i = blockIdx.x * 256 + t;
  int v = (i < n) ? deg[i] : 0;
  buf[t] = v; __syncthreads();
  #pragma unroll
  for (int off = 1; off < 256; off <<= 1){
    int x = (t >= off) ? buf[t - off] : 0;
    __syncthreads(); buf[t] += x; __syncthreads();
  }
  if (i < n) part[i] = buf[t] - v;
  if (t == 255) sums[blockIdx.x] = buf[255];
}

__global__ void k_scan_top(int* __restrict__ sums, int nb){
  __shared__ int buf[256];
  int t = threadIdx.x;
  int v = (t < nb) ? sums[t] : 0;
  buf[t] = v; __syncthreads();
  #pragma unroll
  for (int off = 1; off < 256; off <<= 1){
    int x = (t >= off) ? buf[t - off] : 0;
    __syncthreads(); buf[t] += x; __syncthreads();
  }
  if (t < nb) sums[t] = buf[t] - v;
}

__global__ void k_scan_add(int* __restrict__ ptr, const int* __restrict__ sums,
                           int n, int Etot){
  int i = blockIdx.x * 256 + threadIdx.x;
  if (i < n) ptr[i] += sums[blockIdx.x];
  if (i == 0) ptr[n] = Etot;
}

// CSR fill: scatter src/dst AND the edge_attr row into CSR order (cea).
__global__ void k_fill(const int* __restrict__ dst, const int* __restrict__ src,
                       int* __restrict__ cnt, const int* __restrict__ ptr,
                       const float* __restrict__ ea, float* __restrict__ cea,
                       int* __restrict__ sx, int* __restrict__ dx, int E){
  int e = blockIdx.x * blockDim.x + threadIdx.x;
  if (e < E){
    int d = dst[e];
    int pos = atomicAdd(&cnt[d], 1);
    int p = ptr[d] + pos;
    sx[p] = src[e];
    dx[p] = d;
    const float4* s4 = (const float4*)(ea + (size_t)e * 16);
    float4* d4 = (float4*)(cea + (size_t)p * 16);
    d4[0] = s4[0]; d4[1] = s4[1]; d4[2] = s4[2]; d4[3] = s4[3];
  }
}

// loop_attr: wave per node; writes mean row into cea[E+node]; extends sx/dx.
__launch_bounds__(256)
__global__ void k_loop_attr(float* __restrict__ cea, const int* __restrict__ ptr,
                            int* __restrict__ sx, int* __restrict__ dx, int N, int E){
  int node = blockIdx.x * 4 + (threadIdx.x >> 6);
  if (node >= N) return;
  int t = threadIdx.x & 63;
  int dim = t & 15, slot = t >> 4;
  int beg = ptr[node], end = ptr[node + 1];
  float s = 0.f;
  for (int i = beg + slot; i < end; i += 4)
    s += cea[(size_t)i * 16 + dim];
  s += __shfl_xor(s, 16);
  s += __shfl_xor(s, 32);
  if (slot == 0){
    float dg = (float)(end - beg);
    cea[(size_t)(E + node) * 16 + dim] = s / fmaxf(dg, 1.0f);
  }
  if (t == 0){ sx[E + node] = node; dx[E + node] = node; }
}

// ---------------- Y[M,128] = X[M,128] @ W[128,128] + b (packed fp32) ----------------
__launch_bounds__(256)
__global__ void k_gemm128(const float* __restrict__ X, const float* __restrict__ W,
                          const float* __restrict__ bias, float* __restrict__ Y, int M){
  __shared__ float Xs[64][129];
  int t = threadIdx.x;
  int rowBase = blockIdx.x * 64;
  int lr = t >> 5, lc = (t & 31) * 4;
  #pragma unroll
  for (int p = 0; p < 8; p++){
    int r = p * 8 + lr, gr = rowBase + r;
    float4 v = make_float4(0.f, 0.f, 0.f, 0.f);
    if (gr < M) v = *(const float4*)(X + (size_t)gr * 128 + lc);
    Xs[r][lc] = v.x; Xs[r][lc + 1] = v.y; Xs[r][lc + 2] = v.z; Xs[r][lc + 3] = v.w;
  }
  __syncthreads();
  int c0 = (t & 31) * 4, r0 = (t >> 5) * 8;
  float4 bv = *(const float4*)(bias + c0);
  f2 acc[8][2];
  #pragma unroll
  for (int i = 0; i < 8; i++){ acc[i][0] = (f2){bv.x, bv.y}; acc[i][1] = (f2){bv.z, bv.w}; }
  for (int k = 0; k < 128; k++){
    float4 wv = *(const float4*)(W + k * 128 + c0);
    f2 w0 = (f2){wv.x, wv.y}, w1 = (f2){wv.z, wv.w};
    #pragma unroll
    for (int i = 0; i < 8; i++){
      f2 xx = sp2(Xs[r0 + i][k]);
      acc[i][0] = fma2(xx, w0, acc[i][0]);
      acc[i][1] = fma2(xx, w1, acc[i][1]);
    }
  }
  #pragma unroll
  for (int i = 0; i < 8; i++){
    int gr = rowBase + r0 + i;
    if (gr < M){
      float4 o; o.x = acc[i][0].x; o.y = acc[i][0].y; o.z = acc[i][1].x; o.w = acc[i][1].y;
      *(float4*)(Y + (size_t)gr * 128 + c0) = o;
    }
  }
}

__launch_bounds__(256)
__global__ void k_gemm_lr(const float* __restrict__ X,
                          const float* __restrict__ WL, const float* __restrict__ bL,
                          const float* __restrict__ WR, const float* __restrict__ bR,
                          float* __restrict__ YL, float* __restrict__ YR, int M){
  __shared__ float Xs[64][129];
  int t = threadIdx.x;
  int rowBase = blockIdx.x * 64;
  int lr = t >> 5, lc = (t & 31) * 4;
  #pragma unroll
  for (int p = 0; p < 8; p++){
    int r = p * 8 + lr, gr = rowBase + r;
    float4 v = make_float4(0.f, 0.f, 0.f, 0.f);
    if (gr < M) v = *(const float4*)(X + (size_t)gr * 128 + lc);
    Xs[r][lc] = v.x; Xs[r][lc + 1] = v.y; Xs[r][lc + 2] = v.z; Xs[r][lc + 3] = v.w;
  }
  __syncthreads();
  int c0 = (t & 31) * 4, r0 = (t >> 5) * 8;
  float4 bv = *(const float4*)(bL + c0);
  float4 cv = *(const float4*)(bR + c0);
  f2 aL[8][2], aR[8][2];
  #pragma unroll
  for (int i = 0; i < 8; i++){
    aL[i][0] = (f2){bv.x, bv.y}; aL[i][1] = (f2){bv.z, bv.w};
    aR[i][0] = (f2){cv.x, cv.y}; aR[i][1] = (f2){cv.z, cv.w};
  }
  for (int k = 0; k < 128; k++){
    float4 wl = *(const float4*)(WL + k * 128 + c0);
    float4 wr = *(const float4*)(WR + k * 128 + c0);
    f2 l0 = (f2){wl.x, wl.y}, l1 = (f2){wl.z, wl.w};
    f2 r0v = (f2){wr.x, wr.y}, r1v = (f2){wr.z, wr.w};
    #pragma unroll
    for (int i = 0; i < 8; i++){
      f2 xx = sp2(Xs[r0 + i][k]);
      aL[i][0] = fma2(xx, l0, aL[i][0]); aL[i][1] = fma2(xx, l1, aL[i][1]);
      aR[i][0] = fma2(xx, r0v, aR[i][0]); aR[i][1] = fma2(xx, r1v, aR[i][1]);
    }
  }
  #pragma unroll
  for (int i = 0; i < 8; i++){
    int gr = rowBase + r0 + i;
    if (gr < M){
      float4 o; o.x = aL[i][0].x; o.y = aL[i][0].y; o.z = aL[i][1].x; o.w = aL[i][1].y;
      *(float4*)(YL + (size_t)gr * 128 + c0) = o;
      float4 q; q.x = aR[i][0].x; q.y = aR[i][0].y; q.z = aR[i][1].x; q.w = aR[i][1].y;
      *(float4*)(YR + (size_t)gr * 128 + c0) = q;
    }
  }
}

// ---------------- Phase P: edge-parallel exp(logits) ----------------
// Items p in [0, M=E+N) in CSR order; p>=E are self loops (cea row p, src=dst).
// Wave owns 64 consecutive items; unroll-2 ping-pong, depth-2 prefetch.
// Writes P[p][h] = exp(logit[p][h]) (no max subtraction: logits are O(1)).
__launch_bounds__(256)
__global__ void k_logits(const float* __restrict__ xl, const float* __restrict__ xr,
                         const float* __restrict__ cea,
                         const int* __restrict__ sx, const int* __restrict__ dx,
                         const float* __restrict__ We, const float* __restrict__ att,
                         float* __restrict__ P, int M){
  const int t = threadIdx.x & 63;
  const int base = (blockIdx.x * 4 + (threadIdx.x >> 6)) * 64;
  if (base >= M) return;
  const int cnt = min(64, M - base);

  f2 we[16];
  #pragma unroll
  for (int k = 0; k < 16; k++) we[k] = (f2){We[k * 128 + t], We[k * 128 + 64 + t]};
  const f2 attv = (f2){att[t], att[64 + t]};

  int sl = 0, dl = 0;
  if (base + t < M){ sl = sx[base + t]; dl = dx[base + t]; }
  const float* ceab = cea + (size_t)base * 16;

  auto proc = [&](int i, f2 Xc, f2 Rc, float4 B0, float4 B1, float4 B2, float4 B3){
    f2 ee = sp2(B0.x) * we[0];
    ee = fma2(sp2(B0.y), we[1],  ee); ee = fma2(sp2(B0.z), we[2],  ee); ee = fma2(sp2(B0.w), we[3],  ee);
    ee = fma2(sp2(B1.x), we[4],  ee); ee = fma2(sp2(B1.y), we[5],  ee); ee = fma2(sp2(B1.z), we[6],  ee);
    ee = fma2(sp2(B1.w), we[7],  ee); ee = fma2(sp2(B2.x), we[8],  ee); ee = fma2(sp2(B2.y), we[9],  ee);
    ee = fma2(sp2(B2.z), we[10], ee); ee = fma2(sp2(B2.w), we[11], ee); ee = fma2(sp2(B3.x), we[12], ee);
    ee = fma2(sp2(B3.y), we[13], ee); ee = fma2(sp2(B3.z), we[14], ee); ee = fma2(sp2(B3.w), we[15], ee);
    f2 m = Xc + Rc + ee;
    m = fma2(sp2(NEG_SLOPE), min2(m, sp2(0.f)), max2(m, sp2(0.f)));  // LeakyReLU
    f2 pr = m * attv;
    float l0 = gsum32(pr.x);   // lanes 0-31: h0 ; 32-63: h1
    float l1 = gsum32(pr.y);   // lanes 0-31: h2 ; 32-63: h3
    if ((t & 31) == 0){
      size_t q = (size_t)(base + i) * 4 + (t >> 5);
      P[q]     = __expf(l0);
      P[q + 2] = __expf(l1);
    }
  };

  // fetch slot0 (item 0)
  int s0 = rlI(sl, 0), d0 = rlI(dl, 0);
  const float *xq = xl + (size_t)s0 * 128, *rq = xr + (size_t)d0 * 128;
  f2 X0 = (f2){xq[t], xq[64 + t]}, R0 = (f2){rq[t], rq[64 + t]};
  const float4* ep = (const float4*)ceab;
  float4 A00 = ep[0], A01 = ep[1], A02 = ep[2], A03 = ep[3];
  // fetch slot1 (item 1)
  f2 X1 = sp2(0.f), R1 = sp2(0.f);
  float4 A10 = A00, A11 = A01, A12 = A02, A13 = A03;
  if (cnt > 1){
    int s1 = rlI(sl, 1), d1 = rlI(dl, 1);
    const float *x2 = xl + (size_t)s1 * 128, *r2 = xr + (size_t)d1 * 128;
    X1 = (f2){x2[t], x2[64 + t]}; R1 = (f2){r2[t], r2[64 + t]};
    const float4* e2 = (const float4*)(ceab + 16);
    A10 = e2[0]; A11 = e2[1]; A12 = e2[2]; A13 = e2[3];
  }

  int i = 0;
  while (true){
    {
      f2 Xc = X0, Rc = R0;
      float4 B0 = A00, B1 = A01, B2 = A02, B3 = A03;
      if (i + 2 < cnt){
        int s = rlI(sl, i + 2), d = rlI(dl, i + 2);
        const float *xp2 = xl + (size_t)s * 128, *rp2 = xr + (size_t)d * 128;
        X0 = (f2){xp2[t], xp2[64 + t]}; R0 = (f2){rp2[t], rp2[64 + t]};
        const float4* e2 = (const float4*)(ceab + (size_t)(i + 2) * 16);
        A00 = e2[0]; A01 = e2[1]; A02 = e2[2]; A03 = e2[3];
      }
      proc(i, Xc, Rc, B0, B1, B2, B3);
    }
    if (++i >= cnt) break;
    {
      f2 Xc = X1, Rc = R1;
      float4 B0 = A10, B1 = A11, B2 = A12, B3 = A13;
      if (i + 2 < cnt){
        int s = rlI(sl, i + 2), d = rlI(dl, i + 2);
        const float *xp2 = xl + (size_t)s * 128, *rp2 = xr + (size_t)d * 128;
        X1 = (f2){xp2[t], xp2[64 + t]}; R1 = (f2){rp2[t], rp2[64 + t]};
        const float4* e2 = (const float4*)(ceab + (size_t)(i + 2) * 16);
        A10 = e2[0]; A11 = e2[1]; A12 = e2[2]; A13 = e2[3];
      }
      proc(i, Xc, Rc, B0, B1, B2, B3);
    }
    if (++i >= cnt) break;
  }
}

// ---------------- Phase S: node-parallel normalize + aggregate ----------------
__launch_bounds__(256)
__global__ void k_agg(const float* __restrict__ xl, const int* __restrict__ sx,
                      const int* __restrict__ ptr, const float* __restrict__ P,
                      const float* __restrict__ cb, float* __restrict__ hout,
                      int N, int E){
  const int t = threadIdx.x & 63;
  const int n = blockIdx.x * 4 + (threadIdx.x >> 6);
  if (n >= N) return;
  const bool lo = (t < 32);
  const int beg = __builtin_amdgcn_readfirstlane(ptr[n]);
  const int end = __builtin_amdgcn_readfirstlane(ptr[n + 1]);
  const int deg = end - beg;
  const float4* P4 = (const float4*)P;

  // denominator: coalesced sum of exp-logits (lane t owns pos beg+t, +64, ...)
  float4 L0 = make_float4(0.f, 0.f, 0.f, 0.f);
  int sv0 = 0;
  if (t < deg){ L0 = P4[(size_t)beg + t]; sv0 = sx[beg + t]; }
  float4 pd = L0;
  for (int b = 64; b < deg; b += 64){
    if (t + b < deg){
      float4 L = P4[(size_t)beg + b + t];
      pd.x += L.x; pd.y += L.y; pd.z += L.z; pd.w += L.w;
    }
  }
  float4 sf = P4[(size_t)E + n];   // self-loop exp-logits
  float rd0 = 1.f / (wsum64(pd.x) + sf.x);
  float rd1 = 1.f / (wsum64(pd.y) + sf.y);
  float rd2 = 1.f / (wsum64(pd.z) + sf.z);
  float rd3 = 1.f / (wsum64(pd.w) + sf.w);
  const f2 rdsel = (f2){ lo ? rd0 : rd1, lo ? rd2 : rd3 };

  // self contribution
  f2 xs = (f2){xl[(size_t)n * 128 + t], xl[(size_t)n * 128 + 64 + t]};
  f2 aself = (f2){ lo ? sf.x : sf.y, lo ? sf.z : sf.w } * rdsel;
  f2 acc = aself * xs;

  // aggregation, dist-2 prefetch of xl gathers
  for (int b = 0; b < deg; b += 64){
    int cnt2 = min(64, deg - b);
    int sv; float4 a4;
    if (b == 0){ sv = sv0; a4 = L0; }
    else {
      sv = 0; a4 = make_float4(0.f, 0.f, 0.f, 0.f);
      if (t < cnt2){ sv = sx[beg + b + t]; a4 = P4[(size_t)beg + b + t]; }
    }
    int sA = rlI(sv, 0);
    f2 g0 = (f2){xl[(size_t)sA * 128 + t], xl[(size_t)sA * 128 + 64 + t]};
    f2 g1 = sp2(0.f);
    if (cnt2 > 1){
      int sB = rlI(sv, 1);
      g1 = (f2){xl[(size_t)sB * 128 + t], xl[(size_t)sB * 128 + 64 + t]};
    }
    for (int i = 0; i < cnt2; i++){
      f2 g = (i & 1) ? g1 : g0;
      if (i + 2 < cnt2){
        int sN = rlI(sv, i + 2);
        f2 gn = (f2){xl[(size_t)sN * 128 + t], xl[(size_t)sN * 128 + 64 + t]};
        if (i & 1) g1 = gn; else g0 = gn;
      }
      float a0 = rlF(a4.x, i), a1 = rlF(a4.y, i), a2 = rlF(a4.z, i), a3 = rlF(a4.w, i);
      f2 aa = (f2){ lo ? a0 : a1, lo ? a2 : a3 } * rdsel;
      acc = fma2(aa, g, acc);
    }
  }

  f2 o = acc + (f2){cb[t], cb[64 + t]};
  float o0 = o.x > 0.f ? o.x : expm1f(o.x);
  float o1 = o.y > 0.f ? o.y : expm1f(o.y);
  hout[(size_t)n * 128 + t] = o0;
  hout[(size_t)n * 128 + 64 + t] = o1;
}

// ---------------- LayerNorm + ReLU-MLP head ----------------
__launch_bounds__(256)
__global__ void k_head(const float* __restrict__ h, const float* __restrict__ g,
                       const float* __restrict__ b, const float* __restrict__ w1,
                       const float* __restrict__ b1, const float* __restrict__ w2,
                       const float* __restrict__ b2, float* __restrict__ out, int N){
  __shared__ float sn[4][128];
  const int t = threadIdx.x & 63, wv = threadIdx.x >> 6;
  const int node = blockIdx.x * 4 + wv;
  float h0 = 0.f, h1 = 0.f;
  if (node < N){ h0 = h[(size_t)node * 128 + t]; h1 = h[(size_t)node * 128 + 64 + t]; }
  float mu = wsum64(h0 + h1) * (1.f / 128.f);
  float d0 = h0 - mu, d1 = h1 - mu;
  float var = wsum64(d0 * d0 + d1 * d1) * (1.f / 128.f);
  float rstd = rsqrtf(var + LN_EPS);
  sn[wv][t]      = d0 * rstd * g[t]      + b[t];
  sn[wv][t + 64] = d1 * rstd * g[t + 64] + b[t + 64];
  __syncthreads();
  float a = b1[t];
  #pragma unroll
  for (int k4 = 0; k4 < 32; k4++){
    float4 v = *(const float4*)&sn[wv][k4 * 4];
    a = fmaf(v.x, w1[(k4 * 4 + 0) * 64 + t], a);
    a = fmaf(v.y, w1[(k4 * 4 + 1) * 64 + t], a);
    a = fmaf(v.z, w1[(k4 * 4 + 2) * 64 + t], a);
    a = fmaf(v.w, w1[(k4 * 4 + 3) * 64 + t], a);
  }
  a = fmaxf(a, 0.f);
  float p0 = a * w2[t * 3 + 0], p1 = a * w2[t * 3 + 1], p2 = a * w2[t * 3 + 2];
  p0 = wsum64(p0); p1 = wsum64(p1); p2 = wsum64(p2);
  if (node < N && t == 0){
    out[(size_t)node * 3 + 0] = p0 + b2[0];
    out[(size_t)node * 3 + 1] = p1 + b2[1];
    out[(size_t)node * 3 + 2] = p2 + b2[2];
  }
}

extern "C" void kernel_launch(void* const* d_in, const int* in_sizes, int n_in,
                              void* d_out, int out_size, void* d_ws, size_t ws_size,
                              hipStream_t stream){
  const float* x    = (const float*)d_in[0];
  const int*   ei   = (const int*)d_in[1];
  const float* ea   = (const float*)d_in[2];
  const float* in_w = (const float*)d_in[3];
  const float* in_b = (const float*)d_in[4];
  const float* Wl   = (const float*)d_in[5];
  const float* bl   = (const float*)d_in[6];
  const float* Wr   = (const float*)d_in[7];
  const float* br   = (const float*)d_in[8];
  const float* We   = (const float*)d_in[9];
  const float* att  = (const float*)d_in[10];
  const float* cb   = (const float*)d_in[11];
  const float* lng  = (const float*)d_in[12];
  const float* lnb  = (const float*)d_in[13];
  const float* h1w  = (const float*)d_in[14];
  const float* h1b  = (const float*)d_in[15];
  const float* h2w  = (const float*)d_in[16];
  const float* h2b  = (const float*)d_in[17];
  float* out = (float*)d_out;

  int N = in_sizes[0] / 128;
  int E = in_sizes[1] / 2;
  int M = E + N;
  const int* src = ei;
  const int* dst = ei + E;

  char* w = (char*)d_ws;
  size_t off = 0;
  auto alloc = [&](size_t bytes) -> char* {
    char* p = w + off;
    off = (off + bytes + 255) & ~(size_t)255;
    return p;
  };
  int*   deg   = (int*)alloc((size_t)N * 4);
  int*   cnt   = (int*)alloc((size_t)N * 4);
  int*   ptr   = (int*)alloc((size_t)(N + 1) * 4);
  int*   bsum  = (int*)alloc(256 * 4);
  int*   sx    = (int*)alloc((size_t)M * 4);
  int*   dx    = (int*)alloc((size_t)M * 4);
  float* cea   = (float*)alloc((size_t)M * 16 * 4);
  float* P     = (float*)alloc((size_t)M * 4 * 4);
  float* h     = (float*)alloc((size_t)N * 128 * 4);
  float* xlb   = (float*)alloc((size_t)N * 128 * 4);
  float* xrb   = (float*)alloc((size_t)N * 128 * 4);

  int nb = (N + 255) / 256;
  hipMemsetAsync(deg, 0, (size_t)N * 4, stream);
  hipMemsetAsync(cnt, 0, (size_t)N * 4, stream);
  k_count<<<(E + 255) / 256, 256, 0, stream>>>(dst, deg, E);
  k_scan_blk<<<nb, 256, 0, stream>>>(deg, ptr, bsum, N);
  k_scan_top<<<1, 256, 0, stream>>>(bsum, nb);
  k_scan_add<<<nb, 256, 0, stream>>>(ptr, bsum, N, E);
  k_fill<<<(E + 255) / 256, 256, 0, stream>>>(dst, src, cnt, ptr, ea, cea, sx, dx, E);
  k_loop_attr<<<(N + 3) / 4, 256, 0, stream>>>(cea, ptr, sx, dx, N, E);

  k_gemm128<<<(N + 63) / 64, 256, 0, stream>>>(x, in_w, in_b, h, N);
  int pblocks = ((M + 63) / 64 + 3) / 4;
  for (int l = 0; l < 2; l++){
    k_gemm_lr<<<(N + 63) / 64, 256, 0, stream>>>(h, Wl + l * 16384, bl + l * 128,
                                                 Wr + l * 16384, br + l * 128, xlb, xrb, N);
    k_logits<<<pblocks, 256, 0, stream>>>(xlb, xrb, cea, sx, dx,
                                          We + l * 2048, att + l * 128, P, M);
    k_agg<<<(N + 3) / 4, 256, 0, stream>>>(xlb, sx, ptr, P, cb + l * 128, h, N, E);
  }
  k_head<<<(N + 3) / 4, 256, 0, stream>>>(h, lng, lnb, h1w, h1b, h2w, h2b, out, N);
}

// Round 6
// 745.860 us; speedup vs baseline: 1.0929x; 1.0929x over previous
//
#include <hip/hip_runtime.h>

#define NEG_SLOPE 0.2f
#define LN_EPS 1e-5f

typedef float f2 __attribute__((ext_vector_type(2)));

__device__ __forceinline__ f2 sp2(float x){ return (f2){x, x}; }
__device__ __forceinline__ f2 fma2(f2 a, f2 b, f2 c){
#if __has_builtin(__builtin_elementwise_fma)
  return __builtin_elementwise_fma(a, b, c);
#else
  f2 r; r.x = fmaf(a.x, b.x, c.x); r.y = fmaf(a.y, b.y, c.y); return r;
#endif
}
__device__ __forceinline__ float wsum64(float v){
  #pragma unroll
  for (int o = 32; o >= 1; o >>= 1) v += __shfl_xor(v, o);
  return v;
}
__device__ __forceinline__ float4 fma4(float a, float4 b, float4 c){
  return make_float4(fmaf(a, b.x, c.x), fmaf(a, b.y, c.y),
                     fmaf(a, b.z, c.z), fmaf(a, b.w, c.w));
}

// ---------------- CSR build ----------------
__global__ void k_count(const int* __restrict__ dst, int* __restrict__ deg, int E){
  int e = blockIdx.x * blockDim.x + threadIdx.x;
  if (e < E) atomicAdd(&deg[dst[e]], 1);
}

__global__ void k_scan_blk(const int* __restrict__ deg, int* __restrict__ part,
                           int* __restrict__ sums, int n){
  __shared__ int buf[256];
  int t = threadIdx.x, i = blockIdx.x * 256 + t;
  int v = (i < n) ? deg[i] : 0;
  buf[t] = v; __syncthreads();
  #pragma unroll
  for (int off = 1; off < 256; off <<= 1){
    int x = (t >= off) ? buf[t - off] : 0;
    __syncthreads(); buf[t] += x; __syncthreads();
  }
  if (i < n) part[i] = buf[t] - v;
  if (t == 255) sums[blockIdx.x] = buf[255];
}

__global__ void k_scan_top(int* __restrict__ sums, int nb){
  __shared__ int buf[256];
  int t = threadIdx.x;
  int v = (t < nb) ? sums[t] : 0;
  buf[t] = v; __syncthreads();
  #pragma unroll
  for (int off = 1; off < 256; off <<= 1){
    int x = (t >= off) ? buf[t - off] : 0;
    __syncthreads(); buf[t] += x; __syncthreads();
  }
  if (t < nb) sums[t] = buf[t] - v;
}

__global__ void k_scan_add(int* __restrict__ ptr, const int* __restrict__ sums,
                           int n, int Etot){
  int i = blockIdx.x * 256 + threadIdx.x;
  if (i < n) ptr[i] += sums[blockIdx.x];
  if (i == 0) ptr[n] = Etot;
}

// CSR fill: scatter src/dst AND the edge_attr row into CSR order (cea).
__global__ void k_fill(const int* __restrict__ dst, const int* __restrict__ src,
                       int* __restrict__ cnt, const int* __restrict__ ptr,
                       const float* __restrict__ ea, float* __restrict__ cea,
                       int* __restrict__ sx, int* __restrict__ dx, int E){
  int e = blockIdx.x * blockDim.x + threadIdx.x;
  if (e < E){
    int d = dst[e];
    int pos = atomicAdd(&cnt[d], 1);
    int p = ptr[d] + pos;
    sx[p] = src[e];
    dx[p] = d;
    const float4* s4 = (const float4*)(ea + (size_t)e * 16);
    float4* d4 = (float4*)(cea + (size_t)p * 16);
    d4[0] = s4[0]; d4[1] = s4[1]; d4[2] = s4[2]; d4[3] = s4[3];
  }
}

// loop_attr: wave per node; writes mean row into cea[E+node]; extends sx/dx.
__launch_bounds__(256)
__global__ void k_loop_attr(float* __restrict__ cea, const int* __restrict__ ptr,
                            int* __restrict__ sx, int* __restrict__ dx, int N, int E){
  int node = blockIdx.x * 4 + (threadIdx.x >> 6);
  if (node >= N) return;
  int t = threadIdx.x & 63;
  int dim = t & 15, slot = t >> 4;
  int beg = ptr[node], end = ptr[node + 1];
  float s = 0.f;
  for (int i = beg + slot; i < end; i += 4)
    s += cea[(size_t)i * 16 + dim];
  s += __shfl_xor(s, 16);
  s += __shfl_xor(s, 32);
  if (slot == 0){
    float dg = (float)(end - beg);
    cea[(size_t)(E + node) * 16 + dim] = s / fmaxf(dg, 1.0f);
  }
  if (t == 0){ sx[E + node] = node; dx[E + node] = node; }
}

// ---------------- Y[M,128] = X[M,128] @ W[128,128] + b (packed fp32) ----------------
__launch_bounds__(256)
__global__ void k_gemm128(const float* __restrict__ X, const float* __restrict__ W,
                          const float* __restrict__ bias, float* __restrict__ Y, int M){
  __shared__ float Xs[64][129];
  int t = threadIdx.x;
  int rowBase = blockIdx.x * 64;
  int lr = t >> 5, lc = (t & 31) * 4;
  #pragma unroll
  for (int p = 0; p < 8; p++){
    int r = p * 8 + lr, gr = rowBase + r;
    float4 v = make_float4(0.f, 0.f, 0.f, 0.f);
    if (gr < M) v = *(const float4*)(X + (size_t)gr * 128 + lc);
    Xs[r][lc] = v.x; Xs[r][lc + 1] = v.y; Xs[r][lc + 2] = v.z; Xs[r][lc + 3] = v.w;
  }
  __syncthreads();
  int c0 = (t & 31) * 4, r0 = (t >> 5) * 8;
  float4 bv = *(const float4*)(bias + c0);
  f2 acc[8][2];
  #pragma unroll
  for (int i = 0; i < 8; i++){ acc[i][0] = (f2){bv.x, bv.y}; acc[i][1] = (f2){bv.z, bv.w}; }
  for (int k = 0; k < 128; k++){
    float4 wv = *(const float4*)(W + k * 128 + c0);
    f2 w0 = (f2){wv.x, wv.y}, w1 = (f2){wv.z, wv.w};
    #pragma unroll
    for (int i = 0; i < 8; i++){
      f2 xx = sp2(Xs[r0 + i][k]);
      acc[i][0] = fma2(xx, w0, acc[i][0]);
      acc[i][1] = fma2(xx, w1, acc[i][1]);
    }
  }
  #pragma unroll
  for (int i = 0; i < 8; i++){
    int gr = rowBase + r0 + i;
    if (gr < M){
      float4 o; o.x = acc[i][0].x; o.y = acc[i][0].y; o.z = acc[i][1].x; o.w = acc[i][1].y;
      *(float4*)(Y + (size_t)gr * 128 + c0) = o;
    }
  }
}

__launch_bounds__(256)
__global__ void k_gemm_lr(const float* __restrict__ X,
                          const float* __restrict__ WL, const float* __restrict__ bL,
                          const float* __restrict__ WR, const float* __restrict__ bR,
                          float* __restrict__ YL, float* __restrict__ YR, int M){
  __shared__ float Xs[64][129];
  int t = threadIdx.x;
  int rowBase = blockIdx.x * 64;
  int lr = t >> 5, lc = (t & 31) * 4;
  #pragma unroll
  for (int p = 0; p < 8; p++){
    int r = p * 8 + lr, gr = rowBase + r;
    float4 v = make_float4(0.f, 0.f, 0.f, 0.f);
    if (gr < M) v = *(const float4*)(X + (size_t)gr * 128 + lc);
    Xs[r][lc] = v.x; Xs[r][lc + 1] = v.y; Xs[r][lc + 2] = v.z; Xs[r][lc + 3] = v.w;
  }
  __syncthreads();
  int c0 = (t & 31) * 4, r0 = (t >> 5) * 8;
  float4 bv = *(const float4*)(bL + c0);
  float4 cv = *(const float4*)(bR + c0);
  f2 aL[8][2], aR[8][2];
  #pragma unroll
  for (int i = 0; i < 8; i++){
    aL[i][0] = (f2){bv.x, bv.y}; aL[i][1] = (f2){bv.z, bv.w};
    aR[i][0] = (f2){cv.x, cv.y}; aR[i][1] = (f2){cv.z, cv.w};
  }
  for (int k = 0; k < 128; k++){
    float4 wl = *(const float4*)(WL + k * 128 + c0);
    float4 wr = *(const float4*)(WR + k * 128 + c0);
    f2 l0 = (f2){wl.x, wl.y}, l1 = (f2){wl.z, wl.w};
    f2 r0v = (f2){wr.x, wr.y}, r1v = (f2){wr.z, wr.w};
    #pragma unroll
    for (int i = 0; i < 8; i++){
      f2 xx = sp2(Xs[r0 + i][k]);
      aL[i][0] = fma2(xx, l0, aL[i][0]); aL[i][1] = fma2(xx, l1, aL[i][1]);
      aR[i][0] = fma2(xx, r0v, aR[i][0]); aR[i][1] = fma2(xx, r1v, aR[i][1]);
    }
  }
  #pragma unroll
  for (int i = 0; i < 8; i++){
    int gr = rowBase + r0 + i;
    if (gr < M){
      float4 o; o.x = aL[i][0].x; o.y = aL[i][0].y; o.z = aL[i][1].x; o.w = aL[i][1].y;
      *(float4*)(YL + (size_t)gr * 128 + c0) = o;
      float4 q; q.x = aR[i][0].x; q.y = aR[i][0].y; q.z = aR[i][1].x; q.w = aR[i][1].y;
      *(float4*)(YR + (size_t)gr * 128 + c0) = q;
    }
  }
}

// ---------------- Phase P: edge-parallel exp(logits), pair-split ----------------
// Each 32-lane half owns one item; lane tl owns channels 4tl..4tl+3 (head = tl>>3).
// sx/dx preloaded lane-parallel (64 items/wave), broadcast via __shfl.
// Writes P[p][h] = exp(logit[p][h]).
__launch_bounds__(256)
__global__ void k_logits(const float* __restrict__ xl, const float* __restrict__ xr,
                         const float* __restrict__ cea,
                         const int* __restrict__ sx, const int* __restrict__ dx,
                         const float* __restrict__ We, const float* __restrict__ att,
                         float* __restrict__ P, int M){
  const int t = threadIdx.x & 63;
  const int tl = t & 31;
  const int half = t >> 5;
  const int base = (blockIdx.x * 4 + (threadIdx.x >> 6)) * 64;
  if (base >= M) return;
  const int cnt = min(64, M - base);

  float4 we[16];
  #pragma unroll
  for (int k = 0; k < 16; k++) we[k] = *(const float4*)(We + k * 128 + tl * 4);
  const float4 attv = *(const float4*)(att + tl * 4);  // att flat [H*C]=[128]

  int sv = 0, dv = 0;
  if (base + t < M){ sv = sx[base + t]; dv = dx[base + t]; }

  const int head = tl >> 3;
  const bool storer = (tl & 7) == 0;
  const int npair = (cnt + 1) >> 1;

  float4 xsA, xrA, a0, a1, a2, a3;
  {
    int it = half; if (it >= cnt) it = 0;
    int s = __shfl(sv, it), d = __shfl(dv, it);
    xsA = *(const float4*)(xl + (size_t)s * 128 + tl * 4);
    xrA = *(const float4*)(xr + (size_t)d * 128 + tl * 4);
    const float4* ep = (const float4*)(cea + (size_t)(base + it) * 16);
    a0 = ep[0]; a1 = ep[1]; a2 = ep[2]; a3 = ep[3];
  }

  for (int j = 0; j < npair; j++){
    float4 xsB, xrB, b0, b1, b2, b3;
    if (j + 1 < npair){
      int it = 2 * (j + 1) + half; if (it >= cnt) it = 0;
      int s = __shfl(sv, it), d = __shfl(dv, it);
      xsB = *(const float4*)(xl + (size_t)s * 128 + tl * 4);
      xrB = *(const float4*)(xr + (size_t)d * 128 + tl * 4);
      const float4* ep = (const float4*)(cea + (size_t)(base + it) * 16);
      b0 = ep[0]; b1 = ep[1]; b2 = ep[2]; b3 = ep[3];
    }
    // ee = sum_k ea[k] * We[k][4tl..]
    float4 ee = make_float4(a0.x * we[0].x, a0.x * we[0].y, a0.x * we[0].z, a0.x * we[0].w);
    ee = fma4(a0.y, we[1], ee);  ee = fma4(a0.z, we[2], ee);  ee = fma4(a0.w, we[3], ee);
    ee = fma4(a1.x, we[4], ee);  ee = fma4(a1.y, we[5], ee);  ee = fma4(a1.z, we[6], ee);
    ee = fma4(a1.w, we[7], ee);  ee = fma4(a2.x, we[8], ee);  ee = fma4(a2.y, we[9], ee);
    ee = fma4(a2.z, we[10], ee); ee = fma4(a2.w, we[11], ee); ee = fma4(a3.x, we[12], ee);
    ee = fma4(a3.y, we[13], ee); ee = fma4(a3.z, we[14], ee); ee = fma4(a3.w, we[15], ee);
    float4 m = make_float4(xsA.x + xrA.x + ee.x, xsA.y + xrA.y + ee.y,
                           xsA.z + xrA.z + ee.z, xsA.w + xrA.w + ee.w);
    // LeakyReLU then dot with att (in-lane over 4 channels)
    float w0 = fmaf(NEG_SLOPE, fminf(m.x, 0.f), fmaxf(m.x, 0.f));
    float w1 = fmaf(NEG_SLOPE, fminf(m.y, 0.f), fmaxf(m.y, 0.f));
    float w2 = fmaf(NEG_SLOPE, fminf(m.z, 0.f), fmaxf(m.z, 0.f));
    float w3 = fmaf(NEG_SLOPE, fminf(m.w, 0.f), fmaxf(m.w, 0.f));
    float pl = attv.x * w0;
    pl = fmaf(attv.y, w1, pl); pl = fmaf(attv.z, w2, pl); pl = fmaf(attv.w, w3, pl);
    // reduce over the 8 lanes of this head
    pl += __shfl_xor(pl, 1);
    pl += __shfl_xor(pl, 2);
    pl += __shfl_xor(pl, 4);
    float p = __expf(pl);
    int it = 2 * j + half;
    if (storer && it < cnt) P[(size_t)(base + it) * 4 + head] = p;
    if (j + 1 < npair){
      xsA = xsB; xrA = xrB; a0 = b0; a1 = b1; a2 = b2; a3 = b3;
    }
  }
}

// ---------------- Phase S: single-pass normalize + aggregate, pair-split ----------------
__launch_bounds__(256)
__global__ void k_agg(const float* __restrict__ xl, const int* __restrict__ sx,
                      const int* __restrict__ ptr, const float* __restrict__ P,
                      const float* __restrict__ cb, float* __restrict__ hout,
                      int N, int E){
  const int t = threadIdx.x & 63;
  const int tl = t & 31, half = t >> 5;
  const int n = blockIdx.x * 4 + (threadIdx.x >> 6);
  if (n >= N) return;
  const int head = tl >> 3;
  const int beg = __builtin_amdgcn_readfirstlane(ptr[n]);
  const int end = __builtin_amdgcn_readfirstlane(ptr[n + 1]);
  const int deg = end - beg;

  float4 acc = make_float4(0.f, 0.f, 0.f, 0.f);
  float den = 0.f;
  if (half == 0){
    float ps = P[(size_t)(E + n) * 4 + head];          // self-loop weight
    float4 xs = *(const float4*)(xl + (size_t)n * 128 + tl * 4);
    acc = make_float4(ps * xs.x, ps * xs.y, ps * xs.z, ps * xs.w);
    den = ps;
  }
  const int npair = (deg + 1) >> 1;
  if (npair > 0){
    float4 xsA; float pA; bool vA;
    {
      int it = half; vA = it < deg;
      int pos = beg + (vA ? it : 0);
      int s = sx[pos];
      pA = P[(size_t)pos * 4 + head];
      xsA = *(const float4*)(xl + (size_t)s * 128 + tl * 4);
    }
    for (int j = 0; j < npair; j++){
      float4 xsB; float pB; bool vB;
      if (j + 1 < npair){
        int it = 2 * (j + 1) + half; vB = it < deg;
        int pos = beg + (vB ? it : 0);
        int s = sx[pos];
        pB = P[(size_t)pos * 4 + head];
        xsB = *(const float4*)(xl + (size_t)s * 128 + tl * 4);
      }
      if (vA){ acc = fma4(pA, xsA, acc); den += pA; }
      if (j + 1 < npair){ xsA = xsB; pA = pB; vA = vB; }
    }
  }
  // combine halves
  acc.x += __shfl_xor(acc.x, 32); acc.y += __shfl_xor(acc.y, 32);
  acc.z += __shfl_xor(acc.z, 32); acc.w += __shfl_xor(acc.w, 32);
  den   += __shfl_xor(den, 32);
  float rd = 1.f / den;
  if (half == 0){
    float4 cbv = *(const float4*)(cb + tl * 4);
    float o0 = fmaf(acc.x, rd, cbv.x); o0 = o0 > 0.f ? o0 : expm1f(o0);
    float o1 = fmaf(acc.y, rd, cbv.y); o1 = o1 > 0.f ? o1 : expm1f(o1);
    float o2 = fmaf(acc.z, rd, cbv.z); o2 = o2 > 0.f ? o2 : expm1f(o2);
    float o3 = fmaf(acc.w, rd, cbv.w); o3 = o3 > 0.f ? o3 : expm1f(o3);
    *(float4*)(hout + (size_t)n * 128 + tl * 4) = make_float4(o0, o1, o2, o3);
  }
}

// ---------------- LayerNorm + ReLU-MLP head ----------------
__launch_bounds__(256)
__global__ void k_head(const float* __restrict__ h, const float* __restrict__ g,
                       const float* __restrict__ b, const float* __restrict__ w1,
                       const float* __restrict__ b1, const float* __restrict__ w2,
                       const float* __restrict__ b2, float* __restrict__ out, int N){
  __shared__ float sn[4][128];
  const int t = threadIdx.x & 63, wv = threadIdx.x >> 6;
  const int node = blockIdx.x * 4 + wv;
  float h0 = 0.f, h1 = 0.f;
  if (node < N){ h0 = h[(size_t)node * 128 + t]; h1 = h[(size_t)node * 128 + 64 + t]; }
  float mu = wsum64(h0 + h1) * (1.f / 128.f);
  float d0 = h0 - mu, d1 = h1 - mu;
  float var = wsum64(d0 * d0 + d1 * d1) * (1.f / 128.f);
  float rstd = rsqrtf(var + LN_EPS);
  sn[wv][t]      = d0 * rstd * g[t]      + b[t];
  sn[wv][t + 64] = d1 * rstd * g[t + 64] + b[t + 64];
  __syncthreads();
  float a = b1[t];
  #pragma unroll
  for (int k4 = 0; k4 < 32; k4++){
    float4 v = *(const float4*)&sn[wv][k4 * 4];
    a = fmaf(v.x, w1[(k4 * 4 + 0) * 64 + t], a);
    a = fmaf(v.y, w1[(k4 * 4 + 1) * 64 + t], a);
    a = fmaf(v.z, w1[(k4 * 4 + 2) * 64 + t], a);
    a = fmaf(v.w, w1[(k4 * 4 + 3) * 64 + t], a);
  }
  a = fmaxf(a, 0.f);
  float p0 = a * w2[t * 3 + 0], p1 = a * w2[t * 3 + 1], p2 = a * w2[t * 3 + 2];
  p0 = wsum64(p0); p1 = wsum64(p1); p2 = wsum64(p2);
  if (node < N && t == 0){
    out[(size_t)node * 3 + 0] = p0 + b2[0];
    out[(size_t)node * 3 + 1] = p1 + b2[1];
    out[(size_t)node * 3 + 2] = p2 + b2[2];
  }
}

extern "C" void kernel_launch(void* const* d_in, const int* in_sizes, int n_in,
                              void* d_out, int out_size, void* d_ws, size_t ws_size,
                              hipStream_t stream){
  const float* x    = (const float*)d_in[0];
  const int*   ei   = (const int*)d_in[1];
  const float* ea   = (const float*)d_in[2];
  const float* in_w = (const float*)d_in[3];
  const float* in_b = (const float*)d_in[4];
  const float* Wl   = (const float*)d_in[5];
  const float* bl   = (const float*)d_in[6];
  const float* Wr   = (const float*)d_in[7];
  const float* br   = (const float*)d_in[8];
  const float* We   = (const float*)d_in[9];
  const float* att  = (const float*)d_in[10];
  const float* cb   = (const float*)d_in[11];
  const float* lng  = (const float*)d_in[12];
  const float* lnb  = (const float*)d_in[13];
  const float* h1w  = (const float*)d_in[14];
  const float* h1b  = (const float*)d_in[15];
  const float* h2w  = (const float*)d_in[16];
  const float* h2b  = (const float*)d_in[17];
  float* out = (float*)d_out;

  int N = in_sizes[0] / 128;
  int E = in_sizes[1] / 2;
  int M = E + N;
  const int* src = ei;
  const int* dst = ei + E;

  char* w = (char*)d_ws;
  size_t off = 0;
  auto alloc = [&](size_t bytes) -> char* {
    char* p = w + off;
    off = (off + bytes + 255) & ~(size_t)255;
    return p;
  };
  int*   deg   = (int*)alloc((size_t)N * 4);
  int*   cnt   = (int*)alloc((size_t)N * 4);
  int*   ptr   = (int*)alloc((size_t)(N + 1) * 4);
  int*   bsum  = (int*)alloc(256 * 4);
  int*   sx    = (int*)alloc((size_t)M * 4);
  int*   dx    = (int*)alloc((size_t)M * 4);
  float* cea   = (float*)alloc((size_t)M * 16 * 4);
  float* P     = (float*)alloc((size_t)M * 4 * 4);
  float* h     = (float*)alloc((size_t)N * 128 * 4);
  float* xlb   = (float*)alloc((size_t)N * 128 * 4);
  float* xrb   = (float*)alloc((size_t)N * 128 * 4);

  int nb = (N + 255) / 256;
  hipMemsetAsync(deg, 0, (size_t)N * 4, stream);
  hipMemsetAsync(cnt, 0, (size_t)N * 4, stream);
  k_count<<<(E + 255) / 256, 256, 0, stream>>>(dst, deg, E);
  k_scan_blk<<<nb, 256, 0, stream>>>(deg, ptr, bsum, N);
  k_scan_top<<<1, 256, 0, stream>>>(bsum, nb);
  k_scan_add<<<nb, 256, 0, stream>>>(ptr, bsum, N, E);
  k_fill<<<(E + 255) / 256, 256, 0, stream>>>(dst, src, cnt, ptr, ea, cea, sx, dx, E);
  k_loop_attr<<<(N + 3) / 4, 256, 0, stream>>>(cea, ptr, sx, dx, N, E);

  k_gemm128<<<(N + 63) / 64, 256, 0, stream>>>(x, in_w, in_b, h, N);
  int pblocks = ((M + 63) / 64 + 3) / 4;
  for (int l = 0; l < 2; l++){
    k_gemm_lr<<<(N + 63) / 64, 256, 0, stream>>>(h, Wl + l * 16384, bl + l * 128,
                                                 Wr + l * 16384, br + l * 128, xlb, xrb, N);
    k_logits<<<pblocks, 256, 0, stream>>>(xlb, xrb, cea, sx, dx,
                                          We + l * 2048, att + l * 128, P, M);
    k_agg<<<(N + 3) / 4, 256, 0, stream>>>(xlb, sx, ptr, P, cb + l * 128, h, N, E);
  }
  k_head<<<(N + 3) / 4, 256, 0, stream>>>(h, lng, lnb, h1w, h1b, h2w, h2b, out, N);
}

// Round 7
// 616.827 us; speedup vs baseline: 1.3215x; 1.2092x over previous
//
#include <hip/hip_runtime.h>

#define NEG_SLOPE 0.2f
#define LN_EPS 1e-5f

typedef float f2 __attribute__((ext_vector_type(2)));
typedef short s16x8 __attribute__((ext_vector_type(8)));
typedef float f32x4 __attribute__((ext_vector_type(4)));

__device__ __forceinline__ f2 sp2(float x){ return (f2){x, x}; }
__device__ __forceinline__ f2 fma2(f2 a, f2 b, f2 c){
#if __has_builtin(__builtin_elementwise_fma)
  return __builtin_elementwise_fma(a, b, c);
#else
  f2 r; r.x = fmaf(a.x, b.x, c.x); r.y = fmaf(a.y, b.y, c.y); return r;
#endif
}
__device__ __forceinline__ f2 max2(f2 a, f2 b){
#if __has_builtin(__builtin_elementwise_max)
  return __builtin_elementwise_max(a, b);
#else
  f2 r; r.x = fmaxf(a.x, b.x); r.y = fmaxf(a.y, b.y); return r;
#endif
}
__device__ __forceinline__ f2 min2(f2 a, f2 b){
#if __has_builtin(__builtin_elementwise_min)
  return __builtin_elementwise_min(a, b);
#else
  f2 r; r.x = fminf(a.x, b.x); r.y = fminf(a.y, b.y); return r;
#endif
}
__device__ __forceinline__ float wsum64(float v){
  #pragma unroll
  for (int o = 32; o >= 1; o >>= 1) v += __shfl_xor(v, o);
  return v;
}
// fp32 -> bf16 round-nearest-even
__device__ __forceinline__ unsigned short f2b(float f){
  unsigned u = __float_as_uint(f);
  return (unsigned short)((u + 0x7fffu + ((u >> 16) & 1u)) >> 16);
}

// ---------------- CSR build ----------------
__global__ void k_count(const int* __restrict__ dst, int* __restrict__ deg, int E){
  int e = blockIdx.x * blockDim.x + threadIdx.x;
  if (e < E) atomicAdd(&deg[dst[e]], 1);
}

__global__ void k_scan_blk(const int* __restrict__ deg, int* __restrict__ part,
                           int* __restrict__ sums, int n){
  __shared__ int buf[256];
  int t = threadIdx.x, i = blockIdx.x * 256 + t;
  int v = (i < n) ? deg[i] : 0;
  buf[t] = v; __syncthreads();
  #pragma unroll
  for (int off = 1; off < 256; off <<= 1){
    int x = (t >= off) ? buf[t - off] : 0;
    __syncthreads(); buf[t] += x; __syncthreads();
  }
  if (i < n) part[i] = buf[t] - v;
  if (t == 255) sums[blockIdx.x] = buf[255];
}

__global__ void k_scan_top(int* __restrict__ sums, int nb){
  __shared__ int buf[256];
  int t = threadIdx.x;
  int v = (t < nb) ? sums[t] : 0;
  buf[t] = v; __syncthreads();
  #pragma unroll
  for (int off = 1; off < 256; off <<= 1){
    int x = (t >= off) ? buf[t - off] : 0;
    __syncthreads(); buf[t] += x; __syncthreads();
  }
  if (t < nb) sums[t] = buf[t] - v;
}

__global__ void k_scan_add(int* __restrict__ ptr, const int* __restrict__ sums,
                           int n, int Etot){
  int i = blockIdx.x * 256 + threadIdx.x;
  if (i < n) ptr[i] += sums[blockIdx.x];
  if (i == 0) ptr[n] = Etot;
}

// CSR fill: scatter src AND the edge_attr row into CSR order (cea).
__global__ void k_fill(const int* __restrict__ dst, const int* __restrict__ src,
                       int* __restrict__ cnt, const int* __restrict__ ptr,
                       const float* __restrict__ ea, float* __restrict__ cea,
                       int* __restrict__ sx, int E){
  int e = blockIdx.x * blockDim.x + threadIdx.x;
  if (e < E){
    int d = dst[e];
    int pos = atomicAdd(&cnt[d], 1);
    int p = ptr[d] + pos;
    sx[p] = src[e];
    const float4* s4 = (const float4*)(ea + (size_t)e * 16);
    float4* d4 = (float4*)(cea + (size_t)p * 16);
    d4[0] = s4[0]; d4[1] = s4[1]; d4[2] = s4[2]; d4[3] = s4[3];
  }
}

// loop_attr: wave per node; writes mean row into cea[E+node].
__launch_bounds__(256)
__global__ void k_loop_attr(float* __restrict__ cea, const int* __restrict__ ptr,
                            int N, int E){
  int node = blockIdx.x * 4 + (threadIdx.x >> 6);
  if (node >= N) return;
  int t = threadIdx.x & 63;
  int dim = t & 15, slot = t >> 4;
  int beg = ptr[node], end = ptr[node + 1];
  float s = 0.f;
  for (int i = beg + slot; i < end; i += 4)
    s += cea[(size_t)i * 16 + dim];
  s += __shfl_xor(s, 16);
  s += __shfl_xor(s, 32);
  if (slot == 0){
    float dg = (float)(end - beg);
    cea[(size_t)(E + node) * 16 + dim] = s / fmaxf(dg, 1.0f);
  }
}

// ---------------- bf16 convert + B-fragment pack ----------------
__global__ void k_cvt(const float* __restrict__ X, unsigned short* __restrict__ Xb,
                      long n4){
  long i = (long)blockIdx.x * blockDim.x + threadIdx.x;
  long i4 = i * 4;
  if (i4 < n4){
    float4 v = *(const float4*)(X + i4);
    ushort4 o; o.x = f2b(v.x); o.y = f2b(v.y); o.z = f2b(v.z); o.w = f2b(v.w);
    *(ushort4*)(Xb + i4) = o;
  }
}

// pack 5 [128,128] row-major fp32 matrices into MFMA B-fragment order:
// Bp[mat][c][q][lane][j] = bf16(W[q*32 + (lane>>4)*8 + j][c*16 + (lane&15)])
__global__ void k_pack(const float* __restrict__ w0, const float* __restrict__ w1,
                       const float* __restrict__ w2, const float* __restrict__ w3,
                       const float* __restrict__ w4, unsigned short* __restrict__ Bp){
  int id = blockIdx.x * blockDim.x + threadIdx.x;
  if (id >= 5 * 2048) return;
  int mat = id >> 11, rem = id & 2047;
  int c = rem >> 8, q = (rem >> 6) & 3, l = rem & 63;
  const float* W = mat == 0 ? w0 : mat == 1 ? w1 : mat == 2 ? w2 : mat == 3 ? w3 : w4;
  unsigned short* o = Bp + ((size_t)mat * 2048 + rem) * 8;
  int kb = q * 32 + (l >> 4) * 8;
  int col = c * 16 + (l & 15);
  #pragma unroll
  for (int j = 0; j < 8; j++) o[j] = f2b(W[(kb + j) * 128 + col]);
}

// ---------------- MFMA GEMM: Y[M,128] = A[M,128](bf16) @ W + b ----------------
__launch_bounds__(256)
__global__ void k_mm(const unsigned short* __restrict__ A,
                     const unsigned short* __restrict__ Bp,
                     const float* __restrict__ bias,
                     unsigned short* __restrict__ Yb, int M){
  const int ln = threadIdx.x & 63;
  const int rowBase = (blockIdx.x * 4 + (threadIdx.x >> 6)) * 16;
  const int r16 = ln & 15, quad = ln >> 4;
  int row = rowBase + r16; if (row >= M) row = M - 1;
  const unsigned short* ap = A + (size_t)row * 128 + quad * 8;
  s16x8 af[4];
  #pragma unroll
  for (int q = 0; q < 4; q++) af[q] = *(const s16x8*)(ap + q * 32);
  f32x4 acc[8];
  #pragma unroll
  for (int c = 0; c < 8; c++){
    acc[c] = (f32x4){0.f, 0.f, 0.f, 0.f};
    #pragma unroll
    for (int q = 0; q < 4; q++){
      s16x8 bf = *(const s16x8*)(Bp + ((size_t)(c * 4 + q) * 64 + ln) * 8);
      acc[c] = __builtin_amdgcn_mfma_f32_16x16x32_bf16(af[q], bf, acc[c], 0, 0, 0);
    }
  }
  #pragma unroll
  for (int c = 0; c < 8; c++){
    int col = c * 16 + r16;
    float bv = bias[col];
    #pragma unroll
    for (int r = 0; r < 4; r++){
      int orow = rowBase + quad * 4 + r;
      if (orow < M) Yb[(size_t)orow * 128 + col] = f2b(acc[c][r] + bv);
    }
  }
}

// fused pair: YL = A@WL + bL ; YR = A@WR + bR  (fp32 outputs)
__launch_bounds__(256)
__global__ void k_mm_lr(const unsigned short* __restrict__ A,
                        const unsigned short* __restrict__ BpL,
                        const unsigned short* __restrict__ BpR,
                        const float* __restrict__ bL, const float* __restrict__ bR,
                        float* __restrict__ YL, float* __restrict__ YR, int M){
  const int ln = threadIdx.x & 63;
  const int rowBase = (blockIdx.x * 4 + (threadIdx.x >> 6)) * 16;
  const int r16 = ln & 15, quad = ln >> 4;
  int row = rowBase + r16; if (row >= M) row = M - 1;
  const unsigned short* ap = A + (size_t)row * 128 + quad * 8;
  s16x8 af[4];
  #pragma unroll
  for (int q = 0; q < 4; q++) af[q] = *(const s16x8*)(ap + q * 32);
  f32x4 aL[8], aR[8];
  #pragma unroll
  for (int c = 0; c < 8; c++){
    aL[c] = (f32x4){0.f, 0.f, 0.f, 0.f};
    aR[c] = (f32x4){0.f, 0.f, 0.f, 0.f};
    #pragma unroll
    for (int q = 0; q < 4; q++){
      s16x8 bfl = *(const s16x8*)(BpL + ((size_t)(c * 4 + q) * 64 + ln) * 8);
      s16x8 bfr = *(const s16x8*)(BpR + ((size_t)(c * 4 + q) * 64 + ln) * 8);
      aL[c] = __builtin_amdgcn_mfma_f32_16x16x32_bf16(af[q], bfl, aL[c], 0, 0, 0);
      aR[c] = __builtin_amdgcn_mfma_f32_16x16x32_bf16(af[q], bfr, aR[c], 0, 0, 0);
    }
  }
  #pragma unroll
  for (int c = 0; c < 8; c++){
    int col = c * 16 + r16;
    float bvl = bL[col], bvr = bR[col];
    #pragma unroll
    for (int r = 0; r < 4; r++){
      int orow = rowBase + quad * 4 + r;
      if (orow < M){
        YL[(size_t)orow * 128 + col] = aL[c][r] + bvl;
        YR[(size_t)orow * 128 + col] = aR[c][r] + bvr;
      }
    }
  }
}

// ---------------- Fused GAT layer: wave/node, pair-split, single-pass ----------------
// Half-wave owns one edge item; lane tl owns channels 4tl..4tl+3 (head = tl>>3).
// p = exp(logit) (no max subtraction), out = (sum p*xl[src] + p_self*xl[n]) / sum p.
#define EE16(A0, A1, A2, A3, EA, EB) { \
  EA = sp2(A0.x) * wea[0];            EB = sp2(A0.x) * web[0]; \
  EA = fma2(sp2(A0.y), wea[1], EA);   EB = fma2(sp2(A0.y), web[1], EB); \
  EA = fma2(sp2(A0.z), wea[2], EA);   EB = fma2(sp2(A0.z), web[2], EB); \
  EA = fma2(sp2(A0.w), wea[3], EA);   EB = fma2(sp2(A0.w), web[3], EB); \
  EA = fma2(sp2(A1.x), wea[4], EA);   EB = fma2(sp2(A1.x), web[4], EB); \
  EA = fma2(sp2(A1.y), wea[5], EA);   EB = fma2(sp2(A1.y), web[5], EB); \
  EA = fma2(sp2(A1.z), wea[6], EA);   EB = fma2(sp2(A1.z), web[6], EB); \
  EA = fma2(sp2(A1.w), wea[7], EA);   EB = fma2(sp2(A1.w), web[7], EB); \
  EA = fma2(sp2(A2.x), wea[8], EA);   EB = fma2(sp2(A2.x), web[8], EB); \
  EA = fma2(sp2(A2.y), wea[9], EA);   EB = fma2(sp2(A2.y), web[9], EB); \
  EA = fma2(sp2(A2.z), wea[10], EA);  EB = fma2(sp2(A2.z), web[10], EB); \
  EA = fma2(sp2(A2.w), wea[11], EA);  EB = fma2(sp2(A2.w), web[11], EB); \
  EA = fma2(sp2(A3.x), wea[12], EA);  EB = fma2(sp2(A3.x), web[12], EB); \
  EA = fma2(sp2(A3.y), wea[13], EA);  EB = fma2(sp2(A3.y), web[13], EB); \
  EA = fma2(sp2(A3.z), wea[14], EA);  EB = fma2(sp2(A3.z), web[14], EB); \
  EA = fma2(sp2(A3.w), wea[15], EA);  EB = fma2(sp2(A3.w), web[15], EB); }

__launch_bounds__(256)
__global__ void k_gat(const float* __restrict__ xl, const float* __restrict__ xr,
                      const float* __restrict__ cea, const int* __restrict__ sx,
                      const int* __restrict__ ptr,
                      const float* __restrict__ We, const float* __restrict__ att,
                      const float* __restrict__ cbv,
                      float* __restrict__ hf, unsigned short* __restrict__ hb,
                      int N, int E, int wf, int wb){
  const int t = threadIdx.x & 63;
  const int n = blockIdx.x * 4 + (threadIdx.x >> 6);
  if (n >= N) return;
  const int tl = t & 31, half = t >> 5;
  const int c0 = tl * 4;

  f2 wea[16], web[16];
  #pragma unroll
  for (int k = 0; k < 16; k++){
    wea[k] = *(const f2*)(We + k * 128 + c0);
    web[k] = *(const f2*)(We + k * 128 + c0 + 2);
  }
  const f2 ata = *(const f2*)(att + c0);
  const f2 atb = *(const f2*)(att + c0 + 2);

  const int beg = __builtin_amdgcn_readfirstlane(ptr[n]);
  const int end = __builtin_amdgcn_readfirstlane(ptr[n + 1]);

  const float4 xr4 = *(const float4*)(xr + (size_t)n * 128 + c0);
  const f2 xra = (f2){xr4.x, xr4.y}, xrb = (f2){xr4.z, xr4.w};

  f2 acca, accb; float den;
  {
    // self loop: ea = mean row cea[E+n], src = dst = n
    const float4* lp = (const float4*)(cea + (size_t)(E + n) * 16);
    float4 a0 = lp[0], a1 = lp[1], a2 = lp[2], a3 = lp[3];
    float4 xs4 = *(const float4*)(xl + (size_t)n * 128 + c0);
    f2 xsa = (f2){xs4.x, xs4.y}, xsb = (f2){xs4.z, xs4.w};
    f2 ea, eb;
    EE16(a0, a1, a2, a3, ea, eb);
    f2 ma = xsa + xra + ea, mb = xsb + xrb + eb;
    ma = fma2(sp2(NEG_SLOPE), min2(ma, sp2(0.f)), max2(ma, sp2(0.f)));
    mb = fma2(sp2(NEG_SLOPE), min2(mb, sp2(0.f)), max2(mb, sp2(0.f)));
    f2 pr = fma2(mb, atb, ma * ata);
    float pl = pr.x + pr.y;
    pl += __shfl_xor(pl, 1); pl += __shfl_xor(pl, 2); pl += __shfl_xor(pl, 4);
    float p = (half == 0) ? __expf(pl) : 0.f;
    den = p;
    acca = sp2(p) * xsa;
    accb = sp2(p) * xsb;
  }

  for (int cb2 = beg; cb2 < end; cb2 += 64){
    const int cn = __builtin_amdgcn_readfirstlane(min(64, end - cb2));
    int sv = (t < cn) ? sx[cb2 + t] : 0;
    const int np = (cn + 1) >> 1;
    // preload slot A (item = half)
    int i = half;
    bool vA = i < cn;
    int ic = vA ? i : 0;
    int s = __shfl(sv, ic);
    const float4* ep = (const float4*)(cea + (size_t)(cb2 + ic) * 16);
    float4 A0 = ep[0], A1 = ep[1], A2 = ep[2], A3 = ep[3];
    float4 xs4 = *(const float4*)(xl + (size_t)s * 128 + c0);
    for (int j = 0; j < np; j++){
      float4 B0, B1, B2, B3, xsB;
      bool vB = false;
      if (j + 1 < np){
        int i2 = 2 * (j + 1) + half;
        vB = i2 < cn;
        int ic2 = vB ? i2 : 0;
        int s2 = __shfl(sv, ic2);
        const float4* ep2 = (const float4*)(cea + (size_t)(cb2 + ic2) * 16);
        B0 = ep2[0]; B1 = ep2[1]; B2 = ep2[2]; B3 = ep2[3];
        xsB = *(const float4*)(xl + (size_t)s2 * 128 + c0);
      }
      f2 xsa = (f2){xs4.x, xs4.y}, xsb = (f2){xs4.z, xs4.w};
      f2 ea, eb;
      EE16(A0, A1, A2, A3, ea, eb);
      f2 ma = xsa + xra + ea, mb = xsb + xrb + eb;
      ma = fma2(sp2(NEG_SLOPE), min2(ma, sp2(0.f)), max2(ma, sp2(0.f)));
      mb = fma2(sp2(NEG_SLOPE), min2(mb, sp2(0.f)), max2(mb, sp2(0.f)));
      f2 pr = fma2(mb, atb, ma * ata);
      float pl = pr.x + pr.y;
      pl += __shfl_xor(pl, 1); pl += __shfl_xor(pl, 2); pl += __shfl_xor(pl, 4);
      float p = vA ? __expf(pl) : 0.f;
      den += p;
      acca = fma2(sp2(p), xsa, acca);
      accb = fma2(sp2(p), xsb, accb);
      if (j + 1 < np){ A0 = B0; A1 = B1; A2 = B2; A3 = B3; xs4 = xsB; vA = vB; }
    }
  }

  // combine the two halves
  acca.x += __shfl_xor(acca.x, 32); acca.y += __shfl_xor(acca.y, 32);
  accb.x += __shfl_xor(accb.x, 32); accb.y += __shfl_xor(accb.y, 32);
  den    += __shfl_xor(den, 32);

  if (half == 0){
    float rd = 1.f / den;
    const float4 cb4 = *(const float4*)(cbv + c0);
    float o0 = fmaf(acca.x, rd, cb4.x); o0 = o0 > 0.f ? o0 : expm1f(o0);
    float o1 = fmaf(acca.y, rd, cb4.y); o1 = o1 > 0.f ? o1 : expm1f(o1);
    float o2 = fmaf(accb.x, rd, cb4.z); o2 = o2 > 0.f ? o2 : expm1f(o2);
    float o3 = fmaf(accb.y, rd, cb4.w); o3 = o3 > 0.f ? o3 : expm1f(o3);
    if (wf) *(float4*)(hf + (size_t)n * 128 + c0) = make_float4(o0, o1, o2, o3);
    if (wb){
      ushort4 ub; ub.x = f2b(o0); ub.y = f2b(o1); ub.z = f2b(o2); ub.w = f2b(o3);
      *(ushort4*)(hb + (size_t)n * 128 + c0) = ub;
    }
  }
}

// ---------------- LayerNorm + ReLU-MLP head ----------------
__launch_bounds__(256)
__global__ void k_head(const float* __restrict__ h, const float* __restrict__ g,
                       const float* __restrict__ b, const float* __restrict__ w1,
                       const float* __restrict__ b1, const float* __restrict__ w2,
                       const float* __restrict__ b2, float* __restrict__ out, int N){
  __shared__ float sn[4][128];
  const int t = threadIdx.x & 63, wv = threadIdx.x >> 6;
  const int node = blockIdx.x * 4 + wv;
  float h0 = 0.f, h1 = 0.f;
  if (node < N){ h0 = h[(size_t)node * 128 + t]; h1 = h[(size_t)node * 128 + 64 + t]; }
  float mu = wsum64(h0 + h1) * (1.f / 128.f);
  float d0 = h0 - mu, d1 = h1 - mu;
  float var = wsum64(d0 * d0 + d1 * d1) * (1.f / 128.f);
  float rstd = rsqrtf(var + LN_EPS);
  sn[wv][t]      = d0 * rstd * g[t]      + b[t];
  sn[wv][t + 64] = d1 * rstd * g[t + 64] + b[t + 64];
  __syncthreads();
  float a = b1[t];
  #pragma unroll
  for (int k4 = 0; k4 < 32; k4++){
    float4 v = *(const float4*)&sn[wv][k4 * 4];
    a = fmaf(v.x, w1[(k4 * 4 + 0) * 64 + t], a);
    a = fmaf(v.y, w1[(k4 * 4 + 1) * 64 + t], a);
    a = fmaf(v.z, w1[(k4 * 4 + 2) * 64 + t], a);
    a = fmaf(v.w, w1[(k4 * 4 + 3) * 64 + t], a);
  }
  a = fmaxf(a, 0.f);
  float p0 = a * w2[t * 3 + 0], p1 = a * w2[t * 3 + 1], p2 = a * w2[t * 3 + 2];
  p0 = wsum64(p0); p1 = wsum64(p1); p2 = wsum64(p2);
  if (node < N && t == 0){
    out[(size_t)node * 3 + 0] = p0 + b2[0];
    out[(size_t)node * 3 + 1] = p1 + b2[1];
    out[(size_t)node * 3 + 2] = p2 + b2[2];
  }
}

extern "C" void kernel_launch(void* const* d_in, const int* in_sizes, int n_in,
                              void* d_out, int out_size, void* d_ws, size_t ws_size,
                              hipStream_t stream){
  const float* x    = (const float*)d_in[0];
  const int*   ei   = (const int*)d_in[1];
  const float* ea   = (const float*)d_in[2];
  const float* in_w = (const float*)d_in[3];
  const float* in_b = (const float*)d_in[4];
  const float* Wl   = (const float*)d_in[5];
  const float* bl   = (const float*)d_in[6];
  const float* Wr   = (const float*)d_in[7];
  const float* br   = (const float*)d_in[8];
  const float* We   = (const float*)d_in[9];
  const float* att  = (const float*)d_in[10];
  const float* cb   = (const float*)d_in[11];
  const float* lng  = (const float*)d_in[12];
  const float* lnb  = (const float*)d_in[13];
  const float* h1w  = (const float*)d_in[14];
  const float* h1b  = (const float*)d_in[15];
  const float* h2w  = (const float*)d_in[16];
  const float* h2b  = (const float*)d_in[17];
  float* out = (float*)d_out;

  int N = in_sizes[0] / 128;
  int E = in_sizes[1] / 2;
  const int* src = ei;
  const int* dst = ei + E;

  char* w = (char*)d_ws;
  size_t off = 0;
  auto alloc = [&](size_t bytes) -> char* {
    char* p = w + off;
    off = (off + bytes + 255) & ~(size_t)255;
    return p;
  };
  int*   deg   = (int*)alloc((size_t)N * 4);
  int*   cnt   = (int*)alloc((size_t)N * 4);
  int*   ptr   = (int*)alloc((size_t)(N + 1) * 4);
  int*   bsum  = (int*)alloc(256 * 4);
  int*   sx    = (int*)alloc((size_t)E * 4);
  float* cea   = (float*)alloc((size_t)(E + N) * 16 * 4);
  unsigned short* xb    = (unsigned short*)alloc((size_t)N * 128 * 2);  // also layer-0 gat bf16 out
  unsigned short* hb_in = (unsigned short*)alloc((size_t)N * 128 * 2);
  unsigned short* Bp    = (unsigned short*)alloc((size_t)5 * 16384 * 2);
  float* hf    = (float*)alloc((size_t)N * 128 * 4);
  float* xlb   = (float*)alloc((size_t)N * 128 * 4);
  float* xrb   = (float*)alloc((size_t)N * 128 * 4);

  int nb = (N + 255) / 256;
  hipMemsetAsync(deg, 0, (size_t)N * 4, stream);
  hipMemsetAsync(cnt, 0, (size_t)N * 4, stream);
  k_count<<<(E + 255) / 256, 256, 0, stream>>>(dst, deg, E);
  k_scan_blk<<<nb, 256, 0, stream>>>(deg, ptr, bsum, N);
  k_scan_top<<<1, 256, 0, stream>>>(bsum, nb);
  k_scan_add<<<nb, 256, 0, stream>>>(ptr, bsum, N, E);
  k_fill<<<(E + 255) / 256, 256, 0, stream>>>(dst, src, cnt, ptr, ea, cea, sx, E);
  k_loop_attr<<<(N + 3) / 4, 256, 0, stream>>>(cea, ptr, N, E);

  long n4 = (long)N * 128;
  k_cvt<<<(int)((n4 / 4 + 255) / 256), 256, 0, stream>>>(x, xb, n4);
  k_pack<<<(5 * 2048 + 255) / 256, 256, 0, stream>>>(in_w, Wl, Wl + 16384, Wr, Wr + 16384, Bp);

  int gblocks = (N + 63) / 64;
  // in-proj: h = x @ in_w + in_b  (bf16 out)
  k_mm<<<gblocks, 256, 0, stream>>>(xb, Bp, in_b, hb_in, N);
  for (int l = 0; l < 2; l++){
    const unsigned short* Ain = (l == 0) ? hb_in : xb;  // layer-0 gat writes bf16 into xb
    k_mm_lr<<<gblocks, 256, 0, stream>>>(Ain, Bp + (size_t)(1 + l) * 16384,
                                         Bp + (size_t)(3 + l) * 16384,
                                         bl + l * 128, br + l * 128, xlb, xrb, N);
    k_gat<<<(N + 3) / 4, 256, 0, stream>>>(xlb, xrb, cea, sx, ptr,
                                           We + l * 2048, att + l * 128, cb + l * 128,
                                           hf, xb, N, E, (l == 1) ? 1 : 0, (l == 0) ? 1 : 0);
  }
  k_head<<<(N + 3) / 4, 256, 0, stream>>>(hf, lng, lnb, h1w, h1b, h2w, h2b, out, N);
}

// Round 8
// 609.126 us; speedup vs baseline: 1.3382x; 1.0126x over previous
//
#include <hip/hip_runtime.h>

#define NEG_SLOPE 0.2f
#define LN_EPS 1e-5f

typedef float f2 __attribute__((ext_vector_type(2)));
typedef short s16x8 __attribute__((ext_vector_type(8)));
typedef float f32x4 __attribute__((ext_vector_type(4)));

__device__ __forceinline__ f2 sp2(float x){ return (f2){x, x}; }
__device__ __forceinline__ f2 fma2(f2 a, f2 b, f2 c){
#if __has_builtin(__builtin_elementwise_fma)
  return __builtin_elementwise_fma(a, b, c);
#else
  f2 r; r.x = fmaf(a.x, b.x, c.x); r.y = fmaf(a.y, b.y, c.y); return r;
#endif
}
__device__ __forceinline__ f2 max2(f2 a, f2 b){
#if __has_builtin(__builtin_elementwise_max)
  return __builtin_elementwise_max(a, b);
#else
  f2 r; r.x = fmaxf(a.x, b.x); r.y = fmaxf(a.y, b.y); return r;
#endif
}
__device__ __forceinline__ f2 min2(f2 a, f2 b){
#if __has_builtin(__builtin_elementwise_min)
  return __builtin_elementwise_min(a, b);
#else
  f2 r; r.x = fminf(a.x, b.x); r.y = fminf(a.y, b.y); return r;
#endif
}
__device__ __forceinline__ float wsum64(float v){
  #pragma unroll
  for (int o = 32; o >= 1; o >>= 1) v += __shfl_xor(v, o);
  return v;
}
// fp32 -> bf16 round-nearest-even
__device__ __forceinline__ unsigned short f2b(float f){
  unsigned u = __float_as_uint(f);
  return (unsigned short)((u + 0x7fffu + ((u >> 16) & 1u)) >> 16);
}

// ---------------- CSR build ----------------
__global__ void k_count(const int* __restrict__ dst, int* __restrict__ deg, int E){
  int e = blockIdx.x * blockDim.x + threadIdx.x;
  if (e < E) atomicAdd(&deg[dst[e]], 1);
}

__global__ void k_scan_blk(const int* __restrict__ deg, int* __restrict__ part,
                           int* __restrict__ sums, int n){
  __shared__ int buf[256];
  int t = threadIdx.x, i = blockIdx.x * 256 + t;
  int v = (i < n) ? deg[i] : 0;
  buf[t] = v; __syncthreads();
  #pragma unroll
  for (int off = 1; off < 256; off <<= 1){
    int x = (t >= off) ? buf[t - off] : 0;
    __syncthreads(); buf[t] += x; __syncthreads();
  }
  if (i < n) part[i] = buf[t] - v;
  if (t == 255) sums[blockIdx.x] = buf[255];
}

__global__ void k_scan_top(int* __restrict__ sums, int nb){
  __shared__ int buf[256];
  int t = threadIdx.x;
  int v = (t < nb) ? sums[t] : 0;
  buf[t] = v; __syncthreads();
  #pragma unroll
  for (int off = 1; off < 256; off <<= 1){
    int x = (t >= off) ? buf[t - off] : 0;
    __syncthreads(); buf[t] += x; __syncthreads();
  }
  if (t < nb) sums[t] = buf[t] - v;
}

__global__ void k_scan_add(int* __restrict__ ptr, const int* __restrict__ sums,
                           int n, int Etot){
  int i = blockIdx.x * 256 + threadIdx.x;
  if (i < n) ptr[i] += sums[blockIdx.x];
  if (i == 0) ptr[n] = Etot;
}

// CSR fill: scatter src AND the edge_attr row into CSR order (cea).
__global__ void k_fill(const int* __restrict__ dst, const int* __restrict__ src,
                       int* __restrict__ cnt, const int* __restrict__ ptr,
                       const float* __restrict__ ea, float* __restrict__ cea,
                       int* __restrict__ sx, int E){
  int e = blockIdx.x * blockDim.x + threadIdx.x;
  if (e < E){
    int d = dst[e];
    int pos = atomicAdd(&cnt[d], 1);
    int p = ptr[d] + pos;
    sx[p] = src[e];
    const float4* s4 = (const float4*)(ea + (size_t)e * 16);
    float4* d4 = (float4*)(cea + (size_t)p * 16);
    d4[0] = s4[0]; d4[1] = s4[1]; d4[2] = s4[2]; d4[3] = s4[3];
  }
}

// loop_attr: wave per node; writes mean row into cea[E+node].
__launch_bounds__(256)
__global__ void k_loop_attr(float* __restrict__ cea, const int* __restrict__ ptr,
                            int N, int E){
  int node = blockIdx.x * 4 + (threadIdx.x >> 6);
  if (node >= N) return;
  int t = threadIdx.x & 63;
  int dim = t & 15, slot = t >> 4;
  int beg = ptr[node], end = ptr[node + 1];
  float s = 0.f;
  for (int i = beg + slot; i < end; i += 4)
    s += cea[(size_t)i * 16 + dim];
  s += __shfl_xor(s, 16);
  s += __shfl_xor(s, 32);
  if (slot == 0){
    float dg = (float)(end - beg);
    cea[(size_t)(E + node) * 16 + dim] = s / fmaxf(dg, 1.0f);
  }
}

// ---------------- bf16 convert + B-fragment pack ----------------
__global__ void k_cvt(const float* __restrict__ X, unsigned short* __restrict__ Xb,
                      long n4){
  long i = (long)blockIdx.x * blockDim.x + threadIdx.x;
  long i4 = i * 4;
  if (i4 < n4){
    float4 v = *(const float4*)(X + i4);
    ushort4 o; o.x = f2b(v.x); o.y = f2b(v.y); o.z = f2b(v.z); o.w = f2b(v.w);
    *(ushort4*)(Xb + i4) = o;
  }
}

// pack 5 [128,128] row-major fp32 matrices into MFMA B-fragment order:
// Bp[mat][c][q][lane][j] = bf16(W[q*32 + (lane>>4)*8 + j][c*16 + (lane&15)])
__global__ void k_pack(const float* __restrict__ w0, const float* __restrict__ w1,
                       const float* __restrict__ w2, const float* __restrict__ w3,
                       const float* __restrict__ w4, unsigned short* __restrict__ Bp){
  int id = blockIdx.x * blockDim.x + threadIdx.x;
  if (id >= 5 * 2048) return;
  int mat = id >> 11, rem = id & 2047;
  int c = rem >> 8, q = (rem >> 6) & 3, l = rem & 63;
  const float* W = mat == 0 ? w0 : mat == 1 ? w1 : mat == 2 ? w2 : mat == 3 ? w3 : w4;
  unsigned short* o = Bp + ((size_t)mat * 2048 + rem) * 8;
  int kb = q * 32 + (l >> 4) * 8;
  int col = c * 16 + (l & 15);
  #pragma unroll
  for (int j = 0; j < 8; j++) o[j] = f2b(W[(kb + j) * 128 + col]);
}

// ---------------- MFMA GEMM: Y[M,128] = A[M,128](bf16) @ W + b ----------------
__launch_bounds__(256)
__global__ void k_mm(const unsigned short* __restrict__ A,
                     const unsigned short* __restrict__ Bp,
                     const float* __restrict__ bias,
                     unsigned short* __restrict__ Yb, int M){
  const int ln = threadIdx.x & 63;
  const int rowBase = (blockIdx.x * 4 + (threadIdx.x >> 6)) * 16;
  const int r16 = ln & 15, quad = ln >> 4;
  int row = rowBase + r16; if (row >= M) row = M - 1;
  const unsigned short* ap = A + (size_t)row * 128 + quad * 8;
  s16x8 af[4];
  #pragma unroll
  for (int q = 0; q < 4; q++) af[q] = *(const s16x8*)(ap + q * 32);
  f32x4 acc[8];
  #pragma unroll
  for (int c = 0; c < 8; c++){
    acc[c] = (f32x4){0.f, 0.f, 0.f, 0.f};
    #pragma unroll
    for (int q = 0; q < 4; q++){
      s16x8 bf = *(const s16x8*)(Bp + ((size_t)(c * 4 + q) * 64 + ln) * 8);
      acc[c] = __builtin_amdgcn_mfma_f32_16x16x32_bf16(af[q], bf, acc[c], 0, 0, 0);
    }
  }
  #pragma unroll
  for (int c = 0; c < 8; c++){
    int col = c * 16 + r16;
    float bv = bias[col];
    #pragma unroll
    for (int r = 0; r < 4; r++){
      int orow = rowBase + quad * 4 + r;
      if (orow < M) Yb[(size_t)orow * 128 + col] = f2b(acc[c][r] + bv);
    }
  }
}

// fused pair: YL = A@WL + bL ; YR = A@WR + bR  (fp32 outputs)
__launch_bounds__(256)
__global__ void k_mm_lr(const unsigned short* __restrict__ A,
                        const unsigned short* __restrict__ BpL,
                        const unsigned short* __restrict__ BpR,
                        const float* __restrict__ bL, const float* __restrict__ bR,
                        float* __restrict__ YL, float* __restrict__ YR, int M){
  const int ln = threadIdx.x & 63;
  const int rowBase = (blockIdx.x * 4 + (threadIdx.x >> 6)) * 16;
  const int r16 = ln & 15, quad = ln >> 4;
  int row = rowBase + r16; if (row >= M) row = M - 1;
  const unsigned short* ap = A + (size_t)row * 128 + quad * 8;
  s16x8 af[4];
  #pragma unroll
  for (int q = 0; q < 4; q++) af[q] = *(const s16x8*)(ap + q * 32);
  f32x4 aL[8], aR[8];
  #pragma unroll
  for (int c = 0; c < 8; c++){
    aL[c] = (f32x4){0.f, 0.f, 0.f, 0.f};
    aR[c] = (f32x4){0.f, 0.f, 0.f, 0.f};
    #pragma unroll
    for (int q = 0; q < 4; q++){
      s16x8 bfl = *(const s16x8*)(BpL + ((size_t)(c * 4 + q) * 64 + ln) * 8);
      s16x8 bfr = *(const s16x8*)(BpR + ((size_t)(c * 4 + q) * 64 + ln) * 8);
      aL[c] = __builtin_amdgcn_mfma_f32_16x16x32_bf16(af[q], bfl, aL[c], 0, 0, 0);
      aR[c] = __builtin_amdgcn_mfma_f32_16x16x32_bf16(af[q], bfr, aR[c], 0, 0, 0);
    }
  }
  #pragma unroll
  for (int c = 0; c < 8; c++){
    int col = c * 16 + r16;
    float bvl = bL[col], bvr = bR[col];
    #pragma unroll
    for (int r = 0; r < 4; r++){
      int orow = rowBase + quad * 4 + r;
      if (orow < M){
        YL[(size_t)orow * 128 + col] = aL[c][r] + bvl;
        YR[(size_t)orow * 128 + col] = aR[c][r] + bvr;
      }
    }
  }
}

// ---------------- Fused GAT layer ----------------
// Wave handles 4 consecutive nodes (We prologue amortized). Per node: pair-split
// (half-wave per edge item, lane owns 4 channels, head = tl>>3), single-pass
// p = exp(logit) softmax, 3-slot software pipeline (compute j | in-flight j+1 |
// issue j+2) to keep ~3 dependent gather chains outstanding per wave.
#define EE16(A0, A1, A2, A3, EA, EB) { \
  EA = sp2(A0.x) * wea[0];            EB = sp2(A0.x) * web[0]; \
  EA = fma2(sp2(A0.y), wea[1], EA);   EB = fma2(sp2(A0.y), web[1], EB); \
  EA = fma2(sp2(A0.z), wea[2], EA);   EB = fma2(sp2(A0.z), web[2], EB); \
  EA = fma2(sp2(A0.w), wea[3], EA);   EB = fma2(sp2(A0.w), web[3], EB); \
  EA = fma2(sp2(A1.x), wea[4], EA);   EB = fma2(sp2(A1.x), web[4], EB); \
  EA = fma2(sp2(A1.y), wea[5], EA);   EB = fma2(sp2(A1.y), web[5], EB); \
  EA = fma2(sp2(A1.z), wea[6], EA);   EB = fma2(sp2(A1.z), web[6], EB); \
  EA = fma2(sp2(A1.w), wea[7], EA);   EB = fma2(sp2(A1.w), web[7], EB); \
  EA = fma2(sp2(A2.x), wea[8], EA);   EB = fma2(sp2(A2.x), web[8], EB); \
  EA = fma2(sp2(A2.y), wea[9], EA);   EB = fma2(sp2(A2.y), web[9], EB); \
  EA = fma2(sp2(A2.z), wea[10], EA);  EB = fma2(sp2(A2.z), web[10], EB); \
  EA = fma2(sp2(A2.w), wea[11], EA);  EB = fma2(sp2(A2.w), web[11], EB); \
  EA = fma2(sp2(A3.x), wea[12], EA);  EB = fma2(sp2(A3.x), web[12], EB); \
  EA = fma2(sp2(A3.y), wea[13], EA);  EB = fma2(sp2(A3.y), web[13], EB); \
  EA = fma2(sp2(A3.z), wea[14], EA);  EB = fma2(sp2(A3.z), web[14], EB); \
  EA = fma2(sp2(A3.w), wea[15], EA);  EB = fma2(sp2(A3.w), web[15], EB); }

// issue loads for pair JJ of this chunk into slot S
#define LOADPAIR(S, JJ) do { \
  int i2_ = 2 * (JJ) + half; \
  bool v_ = i2_ < cn; \
  int ic_ = v_ ? i2_ : 0; \
  int s2_ = __shfl(sv, ic_); \
  const float4* ep_ = (const float4*)(ceac + (size_t)ic_ * 16); \
  S##a0 = ep_[0]; S##a1 = ep_[1]; S##a2 = ep_[2]; S##a3 = ep_[3]; \
  S##xs = *(const float4*)(xl + (size_t)s2_ * 128 + c0); \
  S##v = v_; \
} while(0)

#define COMPUTE(S) do { \
  f2 xsa = (f2){S##xs.x, S##xs.y}, xsb = (f2){S##xs.z, S##xs.w}; \
  f2 ea, eb; \
  EE16(S##a0, S##a1, S##a2, S##a3, ea, eb); \
  f2 ma = xsa + xra + ea, mb = xsb + xrb + eb; \
  ma = fma2(sp2(NEG_SLOPE), min2(ma, sp2(0.f)), max2(ma, sp2(0.f))); \
  mb = fma2(sp2(NEG_SLOPE), min2(mb, sp2(0.f)), max2(mb, sp2(0.f))); \
  f2 pr = fma2(mb, atb, ma * ata); \
  float pl = pr.x + pr.y; \
  pl += __shfl_xor(pl, 1); pl += __shfl_xor(pl, 2); pl += __shfl_xor(pl, 4); \
  float p = S##v ? __expf(pl) : 0.f; \
  den += p; \
  acca = fma2(sp2(p), xsa, acca); \
  accb = fma2(sp2(p), xsb, accb); \
} while(0)

__launch_bounds__(256)
__global__ void k_gat(const float* __restrict__ xl, const float* __restrict__ xr,
                      const float* __restrict__ cea, const int* __restrict__ sx,
                      const int* __restrict__ ptr,
                      const float* __restrict__ We, const float* __restrict__ att,
                      const float* __restrict__ cbv,
                      float* __restrict__ hf, unsigned short* __restrict__ hb,
                      int N, int E, int wf, int wb){
  const int t = threadIdx.x & 63;
  const int node0 = (blockIdx.x * 4 + (threadIdx.x >> 6)) * 4;
  if (node0 >= N) return;
  const int tl = t & 31, half = t >> 5;
  const int c0 = tl * 4;

  f2 wea[16], web[16];
  #pragma unroll
  for (int k = 0; k < 16; k++){
    wea[k] = *(const f2*)(We + k * 128 + c0);
    web[k] = *(const f2*)(We + k * 128 + c0 + 2);
  }
  const f2 ata = *(const f2*)(att + c0);
  const f2 atb = *(const f2*)(att + c0 + 2);
  const float4 cb4 = *(const float4*)(cbv + c0);

  for (int nn = 0; nn < 4; nn++){
    const int n = node0 + nn;
    if (n >= N) break;
    const int beg = __builtin_amdgcn_readfirstlane(ptr[n]);
    const int end = __builtin_amdgcn_readfirstlane(ptr[n + 1]);

    const float4 xr4 = *(const float4*)(xr + (size_t)n * 128 + c0);
    const f2 xra = (f2){xr4.x, xr4.y}, xrb = (f2){xr4.z, xr4.w};

    f2 acca, accb; float den;
    {
      // self loop: ea = mean row cea[E+n], src = dst = n
      const float4* lp = (const float4*)(cea + (size_t)(E + n) * 16);
      float4 a0 = lp[0], a1 = lp[1], a2 = lp[2], a3 = lp[3];
      float4 xs4 = *(const float4*)(xl + (size_t)n * 128 + c0);
      f2 xsa = (f2){xs4.x, xs4.y}, xsb = (f2){xs4.z, xs4.w};
      f2 ea, eb;
      EE16(a0, a1, a2, a3, ea, eb);
      f2 ma = xsa + xra + ea, mb = xsb + xrb + eb;
      ma = fma2(sp2(NEG_SLOPE), min2(ma, sp2(0.f)), max2(ma, sp2(0.f)));
      mb = fma2(sp2(NEG_SLOPE), min2(mb, sp2(0.f)), max2(mb, sp2(0.f)));
      f2 pr = fma2(mb, atb, ma * ata);
      float pl = pr.x + pr.y;
      pl += __shfl_xor(pl, 1); pl += __shfl_xor(pl, 2); pl += __shfl_xor(pl, 4);
      float p = (half == 0) ? __expf(pl) : 0.f;
      den = p;
      acca = sp2(p) * xsa;
      accb = sp2(p) * xsb;
    }

    for (int cb2 = beg; cb2 < end; cb2 += 64){
      const int cn = __builtin_amdgcn_readfirstlane(min(64, end - cb2));
      int sv = (t < cn) ? sx[cb2 + t] : 0;
      const float* ceac = cea + (size_t)cb2 * 16;
      const int np = (cn + 1) >> 1;

      float4 P0a0, P0a1, P0a2, P0a3, P0xs; bool P0v;
      float4 P1a0, P1a1, P1a2, P1a3, P1xs; bool P1v;
      float4 P2a0, P2a1, P2a2, P2a3, P2xs; bool P2v;
      LOADPAIR(P0, 0);
      if (np > 1) LOADPAIR(P1, 1);

      int j = 0;
      while (true){
        if (j + 2 < np) LOADPAIR(P2, j + 2);
        COMPUTE(P0);
        if (++j >= np) break;
        if (j + 2 < np) LOADPAIR(P0, j + 2);
        COMPUTE(P1);
        if (++j >= np) break;
        if (j + 2 < np) LOADPAIR(P1, j + 2);
        COMPUTE(P2);
        if (++j >= np) break;
      }
    }

    // combine the two halves
    acca.x += __shfl_xor(acca.x, 32); acca.y += __shfl_xor(acca.y, 32);
    accb.x += __shfl_xor(accb.x, 32); accb.y += __shfl_xor(accb.y, 32);
    den    += __shfl_xor(den, 32);

    if (half == 0){
      float rd = 1.f / den;
      float o0 = fmaf(acca.x, rd, cb4.x); o0 = o0 > 0.f ? o0 : expm1f(o0);
      float o1 = fmaf(acca.y, rd, cb4.y); o1 = o1 > 0.f ? o1 : expm1f(o1);
      float o2 = fmaf(accb.x, rd, cb4.z); o2 = o2 > 0.f ? o2 : expm1f(o2);
      float o3 = fmaf(accb.y, rd, cb4.w); o3 = o3 > 0.f ? o3 : expm1f(o3);
      if (wf) *(float4*)(hf + (size_t)n * 128 + c0) = make_float4(o0, o1, o2, o3);
      if (wb){
        ushort4 ub; ub.x = f2b(o0); ub.y = f2b(o1); ub.z = f2b(o2); ub.w = f2b(o3);
        *(ushort4*)(hb + (size_t)n * 128 + c0) = ub;
      }
    }
  }
}

// ---------------- LayerNorm + ReLU-MLP head ----------------
__launch_bounds__(256)
__global__ void k_head(const float* __restrict__ h, const float* __restrict__ g,
                       const float* __restrict__ b, const float* __restrict__ w1,
                       const float* __restrict__ b1, const float* __restrict__ w2,
                       const float* __restrict__ b2, float* __restrict__ out, int N){
  __shared__ float sn[4][128];
  const int t = threadIdx.x & 63, wv = threadIdx.x >> 6;
  const int node = blockIdx.x * 4 + wv;
  float h0 = 0.f, h1 = 0.f;
  if (node < N){ h0 = h[(size_t)node * 128 + t]; h1 = h[(size_t)node * 128 + 64 + t]; }
  float mu = wsum64(h0 + h1) * (1.f / 128.f);
  float d0 = h0 - mu, d1 = h1 - mu;
  float var = wsum64(d0 * d0 + d1 * d1) * (1.f / 128.f);
  float rstd = rsqrtf(var + LN_EPS);
  sn[wv][t]      = d0 * rstd * g[t]      + b[t];
  sn[wv][t + 64] = d1 * rstd * g[t + 64] + b[t + 64];
  __syncthreads();
  float a = b1[t];
  #pragma unroll
  for (int k4 = 0; k4 < 32; k4++){
    float4 v = *(const float4*)&sn[wv][k4 * 4];
    a = fmaf(v.x, w1[(k4 * 4 + 0) * 64 + t], a);
    a = fmaf(v.y, w1[(k4 * 4 + 1) * 64 + t], a);
    a = fmaf(v.z, w1[(k4 * 4 + 2) * 64 + t], a);
    a = fmaf(v.w, w1[(k4 * 4 + 3) * 64 + t], a);
  }
  a = fmaxf(a, 0.f);
  float p0 = a * w2[t * 3 + 0], p1 = a * w2[t * 3 + 1], p2 = a * w2[t * 3 + 2];
  p0 = wsum64(p0); p1 = wsum64(p1); p2 = wsum64(p2);
  if (node < N && t == 0){
    out[(size_t)node * 3 + 0] = p0 + b2[0];
    out[(size_t)node * 3 + 1] = p1 + b2[1];
    out[(size_t)node * 3 + 2] = p2 + b2[2];
  }
}

extern "C" void kernel_launch(void* const* d_in, const int* in_sizes, int n_in,
                              void* d_out, int out_size, void* d_ws, size_t ws_size,
                              hipStream_t stream){
  const float* x    = (const float*)d_in[0];
  const int*   ei   = (const int*)d_in[1];
  const float* ea   = (const float*)d_in[2];
  const float* in_w = (const float*)d_in[3];
  const float* in_b = (const float*)d_in[4];
  const float* Wl   = (const float*)d_in[5];
  const float* bl   = (const float*)d_in[6];
  const float* Wr   = (const float*)d_in[7];
  const float* br   = (const float*)d_in[8];
  const float* We   = (const float*)d_in[9];
  const float* att  = (const float*)d_in[10];
  const float* cb   = (const float*)d_in[11];
  const float* lng  = (const float*)d_in[12];
  const float* lnb  = (const float*)d_in[13];
  const float* h1w  = (const float*)d_in[14];
  const float* h1b  = (const float*)d_in[15];
  const float* h2w  = (const float*)d_in[16];
  const float* h2b  = (const float*)d_in[17];
  float* out = (float*)d_out;

  int N = in_sizes[0] / 128;
  int E = in_sizes[1] / 2;
  const int* src = ei;
  const int* dst = ei + E;

  char* w = (char*)d_ws;
  size_t off = 0;
  auto alloc = [&](size_t bytes) -> char* {
    char* p = w + off;
    off = (off + bytes + 255) & ~(size_t)255;
    return p;
  };
  int*   deg   = (int*)alloc((size_t)N * 4);
  int*   cnt   = (int*)alloc((size_t)N * 4);
  int*   ptr   = (int*)alloc((size_t)(N + 1) * 4);
  int*   bsum  = (int*)alloc(256 * 4);
  int*   sx    = (int*)alloc((size_t)E * 4);
  float* cea   = (float*)alloc((size_t)(E + N) * 16 * 4);
  unsigned short* xb    = (unsigned short*)alloc((size_t)N * 128 * 2);  // also layer-0 gat bf16 out
  unsigned short* hb_in = (unsigned short*)alloc((size_t)N * 128 * 2);
  unsigned short* Bp    = (unsigned short*)alloc((size_t)5 * 16384 * 2);
  float* hf    = (float*)alloc((size_t)N * 128 * 4);
  float* xlb   = (float*)alloc((size_t)N * 128 * 4);
  float* xrb   = (float*)alloc((size_t)N * 128 * 4);

  int nb = (N + 255) / 256;
  hipMemsetAsync(deg, 0, (size_t)N * 4, stream);
  hipMemsetAsync(cnt, 0, (size_t)N * 4, stream);
  k_count<<<(E + 255) / 256, 256, 0, stream>>>(dst, deg, E);
  k_scan_blk<<<nb, 256, 0, stream>>>(deg, ptr, bsum, N);
  k_scan_top<<<1, 256, 0, stream>>>(bsum, nb);
  k_scan_add<<<nb, 256, 0, stream>>>(ptr, bsum, N, E);
  k_fill<<<(E + 255) / 256, 256, 0, stream>>>(dst, src, cnt, ptr, ea, cea, sx, E);
  k_loop_attr<<<(N + 3) / 4, 256, 0, stream>>>(cea, ptr, N, E);

  long n4 = (long)N * 128;
  k_cvt<<<(int)((n4 / 4 + 255) / 256), 256, 0, stream>>>(x, xb, n4);
  k_pack<<<(5 * 2048 + 255) / 256, 256, 0, stream>>>(in_w, Wl, Wl + 16384, Wr, Wr + 16384, Bp);

  int gblocks = (N + 63) / 64;
  // in-proj: h = x @ in_w + in_b  (bf16 out)
  k_mm<<<gblocks, 256, 0, stream>>>(xb, Bp, in_b, hb_in, N);
  for (int l = 0; l < 2; l++){
    const unsigned short* Ain = (l == 0) ? hb_in : xb;  // layer-0 gat writes bf16 into xb
    k_mm_lr<<<gblocks, 256, 0, stream>>>(Ain, Bp + (size_t)(1 + l) * 16384,
                                         Bp + (size_t)(3 + l) * 16384,
                                         bl + l * 128, br + l * 128, xlb, xrb, N);
    k_gat<<<(N + 15) / 16, 256, 0, stream>>>(xlb, xrb, cea, sx, ptr,
                                             We + l * 2048, att + l * 128, cb + l * 128,
                                             hf, xb, N, E, (l == 1) ? 1 : 0, (l == 0) ? 1 : 0);
  }
  k_head<<<(N + 3) / 4, 256, 0, stream>>>(hf, lng, lnb, h1w, h1b, h2w, h2b, out, N);
}

// Round 9
// 589.923 us; speedup vs baseline: 1.3818x; 1.0326x over previous
//
#include <hip/hip_runtime.h>

#define NEG_SLOPE 0.2f
#define LN_EPS 1e-5f

typedef float f2 __attribute__((ext_vector_type(2)));
typedef short s16x8 __attribute__((ext_vector_type(8)));
typedef float f32x4 __attribute__((ext_vector_type(4)));

__device__ __forceinline__ f2 sp2(float x){ return (f2){x, x}; }
__device__ __forceinline__ f2 fma2(f2 a, f2 b, f2 c){
#if __has_builtin(__builtin_elementwise_fma)
  return __builtin_elementwise_fma(a, b, c);
#else
  f2 r; r.x = fmaf(a.x, b.x, c.x); r.y = fmaf(a.y, b.y, c.y); return r;
#endif
}
__device__ __forceinline__ f2 max2(f2 a, f2 b){
#if __has_builtin(__builtin_elementwise_max)
  return __builtin_elementwise_max(a, b);
#else
  f2 r; r.x = fmaxf(a.x, b.x); r.y = fmaxf(a.y, b.y); return r;
#endif
}
__device__ __forceinline__ f2 min2(f2 a, f2 b){
#if __has_builtin(__builtin_elementwise_min)
  return __builtin_elementwise_min(a, b);
#else
  f2 r; r.x = fminf(a.x, b.x); r.y = fminf(a.y, b.y); return r;
#endif
}
__device__ __forceinline__ float wsum64(float v){
  #pragma unroll
  for (int o = 32; o >= 1; o >>= 1) v += __shfl_xor(v, o);
  return v;
}
// fp32 -> bf16 round-nearest-even
__device__ __forceinline__ unsigned short f2b(float f){
  unsigned u = __float_as_uint(f);
  return (unsigned short)((u + 0x7fffu + ((u >> 16) & 1u)) >> 16);
}

// ---------------- CSR build ----------------
__global__ void k_count(const int* __restrict__ dst, int* __restrict__ deg, int E){
  int e = blockIdx.x * blockDim.x + threadIdx.x;
  if (e < E) atomicAdd(&deg[dst[e]], 1);
}

__global__ void k_scan_blk(const int* __restrict__ deg, int* __restrict__ part,
                           int* __restrict__ sums, int n){
  __shared__ int buf[256];
  int t = threadIdx.x, i = blockIdx.x * 256 + t;
  int v = (i < n) ? deg[i] : 0;
  buf[t] = v; __syncthreads();
  #pragma unroll
  for (int off = 1; off < 256; off <<= 1){
    int x = (t >= off) ? buf[t - off] : 0;
    __syncthreads(); buf[t] += x; __syncthreads();
  }
  if (i < n) part[i] = buf[t] - v;
  if (t == 255) sums[blockIdx.x] = buf[255];
}

__global__ void k_scan_top(int* __restrict__ sums, int nb){
  __shared__ int buf[256];
  int t = threadIdx.x;
  int v = (t < nb) ? sums[t] : 0;
  buf[t] = v; __syncthreads();
  #pragma unroll
  for (int off = 1; off < 256; off <<= 1){
    int x = (t >= off) ? buf[t - off] : 0;
    __syncthreads(); buf[t] += x; __syncthreads();
  }
  if (t < nb) sums[t] = buf[t] - v;
}

__global__ void k_scan_add(int* __restrict__ ptr, const int* __restrict__ sums,
                           int n, int Etot){
  int i = blockIdx.x * 256 + threadIdx.x;
  if (i < n) ptr[i] += sums[blockIdx.x];
  if (i == 0) ptr[n] = Etot;
}

// CSR fill: scatter src AND the edge_attr row into CSR order (cea).
__global__ void k_fill(const int* __restrict__ dst, const int* __restrict__ src,
                       int* __restrict__ cnt, const int* __restrict__ ptr,
                       const float* __restrict__ ea, float* __restrict__ cea,
                       int* __restrict__ sx, int E){
  int e = blockIdx.x * blockDim.x + threadIdx.x;
  if (e < E){
    int d = dst[e];
    int pos = atomicAdd(&cnt[d], 1);
    int p = ptr[d] + pos;
    sx[p] = src[e];
    const float4* s4 = (const float4*)(ea + (size_t)e * 16);
    float4* d4 = (float4*)(cea + (size_t)p * 16);
    d4[0] = s4[0]; d4[1] = s4[1]; d4[2] = s4[2]; d4[3] = s4[3];
  }
}

// ---------------- bf16 convert + B-fragment pack ----------------
__global__ void k_cvt(const float* __restrict__ X, unsigned short* __restrict__ Xb,
                      long n4){
  long i = (long)blockIdx.x * blockDim.x + threadIdx.x;
  long i4 = i * 4;
  if (i4 < n4){
    float4 v = *(const float4*)(X + i4);
    ushort4 o; o.x = f2b(v.x); o.y = f2b(v.y); o.z = f2b(v.z); o.w = f2b(v.w);
    *(ushort4*)(Xb + i4) = o;
  }
}

// pack 5 [128,128] row-major fp32 matrices into MFMA B-fragment order:
// Bp[mat][c][q][lane][j] = bf16(W[q*32 + (lane>>4)*8 + j][c*16 + (lane&15)])
__global__ void k_pack(const float* __restrict__ w0, const float* __restrict__ w1,
                       const float* __restrict__ w2, const float* __restrict__ w3,
                       const float* __restrict__ w4, unsigned short* __restrict__ Bp){
  int id = blockIdx.x * blockDim.x + threadIdx.x;
  if (id >= 5 * 2048) return;
  int mat = id >> 11, rem = id & 2047;
  int c = rem >> 8, q = (rem >> 6) & 3, l = rem & 63;
  const float* W = mat == 0 ? w0 : mat == 1 ? w1 : mat == 2 ? w2 : mat == 3 ? w3 : w4;
  unsigned short* o = Bp + ((size_t)mat * 2048 + rem) * 8;
  int kb = q * 32 + (l >> 4) * 8;
  int col = c * 16 + (l & 15);
  #pragma unroll
  for (int j = 0; j < 8; j++) o[j] = f2b(W[(kb + j) * 128 + col]);
}

// ---------------- MFMA GEMM: Y[M,128] = A[M,128](bf16) @ W + b ----------------
__launch_bounds__(256)
__global__ void k_mm(const unsigned short* __restrict__ A,
                     const unsigned short* __restrict__ Bp,
                     const float* __restrict__ bias,
                     unsigned short* __restrict__ Yb, int M){
  const int ln = threadIdx.x & 63;
  const int rowBase = (blockIdx.x * 4 + (threadIdx.x >> 6)) * 16;
  const int r16 = ln & 15, quad = ln >> 4;
  int row = rowBase + r16; if (row >= M) row = M - 1;
  const unsigned short* ap = A + (size_t)row * 128 + quad * 8;
  s16x8 af[4];
  #pragma unroll
  for (int q = 0; q < 4; q++) af[q] = *(const s16x8*)(ap + q * 32);
  f32x4 acc[8];
  #pragma unroll
  for (int c = 0; c < 8; c++){
    acc[c] = (f32x4){0.f, 0.f, 0.f, 0.f};
    #pragma unroll
    for (int q = 0; q < 4; q++){
      s16x8 bf = *(const s16x8*)(Bp + ((size_t)(c * 4 + q) * 64 + ln) * 8);
      acc[c] = __builtin_amdgcn_mfma_f32_16x16x32_bf16(af[q], bf, acc[c], 0, 0, 0);
    }
  }
  #pragma unroll
  for (int c = 0; c < 8; c++){
    int col = c * 16 + r16;
    float bv = bias[col];
    #pragma unroll
    for (int r = 0; r < 4; r++){
      int orow = rowBase + quad * 4 + r;
      if (orow < M) Yb[(size_t)orow * 128 + col] = f2b(acc[c][r] + bv);
    }
  }
}

// fused pair: YL = A@WL + bL ; YR = A@WR + bR  (fp32 outputs)
__launch_bounds__(256)
__global__ void k_mm_lr(const unsigned short* __restrict__ A,
                        const unsigned short* __restrict__ BpL,
                        const unsigned short* __restrict__ BpR,
                        const float* __restrict__ bL, const float* __restrict__ bR,
                        float* __restrict__ YL, float* __restrict__ YR, int M){
  const int ln = threadIdx.x & 63;
  const int rowBase = (blockIdx.x * 4 + (threadIdx.x >> 6)) * 16;
  const int r16 = ln & 15, quad = ln >> 4;
  int row = rowBase + r16; if (row >= M) row = M - 1;
  const unsigned short* ap = A + (size_t)row * 128 + quad * 8;
  s16x8 af[4];
  #pragma unroll
  for (int q = 0; q < 4; q++) af[q] = *(const s16x8*)(ap + q * 32);
  f32x4 aL[8], aR[8];
  #pragma unroll
  for (int c = 0; c < 8; c++){
    aL[c] = (f32x4){0.f, 0.f, 0.f, 0.f};
    aR[c] = (f32x4){0.f, 0.f, 0.f, 0.f};
    #pragma unroll
    for (int q = 0; q < 4; q++){
      s16x8 bfl = *(const s16x8*)(BpL + ((size_t)(c * 4 + q) * 64 + ln) * 8);
      s16x8 bfr = *(const s16x8*)(BpR + ((size_t)(c * 4 + q) * 64 + ln) * 8);
      aL[c] = __builtin_amdgcn_mfma_f32_16x16x32_bf16(af[q], bfl, aL[c], 0, 0, 0);
      aR[c] = __builtin_amdgcn_mfma_f32_16x16x32_bf16(af[q], bfr, aR[c], 0, 0, 0);
    }
  }
  #pragma unroll
  for (int c = 0; c < 8; c++){
    int col = c * 16 + r16;
    float bvl = bL[col], bvr = bR[col];
    #pragma unroll
    for (int r = 0; r < 4; r++){
      int orow = rowBase + quad * 4 + r;
      if (orow < M){
        YL[(size_t)orow * 128 + col] = aL[c][r] + bvl;
        YR[(size_t)orow * 128 + col] = aR[c][r] + bvr;
      }
    }
  }
}

// ---------------- Fused GAT layer: wave/node, full-wave per item ----------------
// Lane t owns channels (2t, 2t+1); head = t>>4 (16 lanes per head).
// Chunk of <=64 CSR items: one coalesced sx load; sub-batches of 16:
//  phase A: 16 independent xl gathers issued back-to-back (v_readlane -> SGPR base)
//  phase B: consume in order (cea rows are sequential broadcast loads).
// Self loop via linearity: ee_self = (sum_e ee_e) / max(deg,1)  [exact algebra],
// so no precomputed loop_attr is needed at all.
#define EE16F2(A0, A1, A2, A3, EE) { \
  EE = sp2(A0.x) * we[0]; \
  EE = fma2(sp2(A0.y), we[1],  EE); EE = fma2(sp2(A0.z), we[2],  EE); \
  EE = fma2(sp2(A0.w), we[3],  EE); EE = fma2(sp2(A1.x), we[4],  EE); \
  EE = fma2(sp2(A1.y), we[5],  EE); EE = fma2(sp2(A1.z), we[6],  EE); \
  EE = fma2(sp2(A1.w), we[7],  EE); EE = fma2(sp2(A2.x), we[8],  EE); \
  EE = fma2(sp2(A2.y), we[9],  EE); EE = fma2(sp2(A2.z), we[10], EE); \
  EE = fma2(sp2(A2.w), we[11], EE); EE = fma2(sp2(A3.x), we[12], EE); \
  EE = fma2(sp2(A3.y), we[13], EE); EE = fma2(sp2(A3.z), we[14], EE); \
  EE = fma2(sp2(A3.w), we[15], EE); }

__launch_bounds__(256)
__global__ void k_gat(const float* __restrict__ xl, const float* __restrict__ xr,
                      const float* __restrict__ cea, const int* __restrict__ sx,
                      const int* __restrict__ ptr,
                      const float* __restrict__ We, const float* __restrict__ att,
                      const float* __restrict__ cbv,
                      float* __restrict__ hf, unsigned short* __restrict__ hb,
                      int N, int E, int wf, int wb){
  const int t = threadIdx.x & 63;
  const int n = blockIdx.x * 4 + (threadIdx.x >> 6);
  if (n >= N) return;
  const int c0 = 2 * t;

  f2 we[16];
  #pragma unroll
  for (int k = 0; k < 16; k++) we[k] = *(const f2*)(We + k * 128 + c0);
  const f2 atv = *(const f2*)(att + c0);
  const f2 cbf = *(const f2*)(cbv + c0);

  const int beg = __builtin_amdgcn_readfirstlane(ptr[n]);
  const int end = __builtin_amdgcn_readfirstlane(ptr[n + 1]);
  const int deg = end - beg;

  const f2 xrv = *(const f2*)(xr + (size_t)n * 128 + c0);
  const f2 xln = *(const f2*)(xl + (size_t)n * 128 + c0);

  f2 acc = sp2(0.f), eesum = sp2(0.f);
  float den = 0.f;

  for (int cbase = beg; cbase < end; cbase += 64){
    const int cn = __builtin_amdgcn_readfirstlane(min(64, end - cbase));
    int sv = (t < cn) ? sx[cbase + t] : 0;
    const float* ceac = cea + (size_t)cbase * 16;

    for (int sub = 0; sub < cn; sub += 16){
      // phase A: issue up to 16 independent gathers (depth-16 in flight)
      f2 xs[16];
      #pragma unroll
      for (int i = 0; i < 16; i++){
        int s = __builtin_amdgcn_readlane(sv, sub + i);   // 0 for invalid slots
        xs[i] = *(const f2*)(xl + (size_t)s * 128 + c0);
      }
      // phase B: consume in order
      #pragma unroll
      for (int i = 0; i < 16; i++){
        if (sub + i < cn){
          const float4* ep = (const float4*)(ceac + (size_t)(sub + i) * 16);
          float4 a0 = ep[0], a1 = ep[1], a2 = ep[2], a3 = ep[3];
          f2 ee;
          EE16F2(a0, a1, a2, a3, ee);
          eesum += ee;
          f2 m = xs[i] + xrv + ee;
          m = fma2(sp2(NEG_SLOPE), min2(m, sp2(0.f)), max2(m, sp2(0.f)));
          f2 pr = m * atv;
          float pl = pr.x + pr.y;
          pl += __shfl_xor(pl, 1); pl += __shfl_xor(pl, 2);
          pl += __shfl_xor(pl, 4); pl += __shfl_xor(pl, 8);
          float p = __expf(pl);
          den += p;
          acc = fma2(sp2(p), xs[i], acc);
        }
      }
    }
  }

  // self loop: ee_self = eesum / max(deg,1)
  {
    float rdeg = 1.f / fmaxf((float)deg, 1.f);
    f2 m = xln + xrv + eesum * sp2(rdeg);
    m = fma2(sp2(NEG_SLOPE), min2(m, sp2(0.f)), max2(m, sp2(0.f)));
    f2 pr = m * atv;
    float pl = pr.x + pr.y;
    pl += __shfl_xor(pl, 1); pl += __shfl_xor(pl, 2);
    pl += __shfl_xor(pl, 4); pl += __shfl_xor(pl, 8);
    float p = __expf(pl);
    den += p;
    acc = fma2(sp2(p), xln, acc);
  }

  float rd = 1.f / den;
  f2 o = fma2(acc, sp2(rd), cbf);
  float o0 = o.x > 0.f ? o.x : expm1f(o.x);
  float o1 = o.y > 0.f ? o.y : expm1f(o.y);
  if (wf) *(f2*)(hf + (size_t)n * 128 + c0) = (f2){o0, o1};
  if (wb){
    unsigned packed = (unsigned)f2b(o0) | ((unsigned)f2b(o1) << 16);
    *(unsigned*)(hb + (size_t)n * 128 + c0) = packed;
  }
}

// ---------------- LayerNorm + ReLU-MLP head ----------------
__launch_bounds__(256)
__global__ void k_head(const float* __restrict__ h, const float* __restrict__ g,
                       const float* __restrict__ b, const float* __restrict__ w1,
                       const float* __restrict__ b1, const float* __restrict__ w2,
                       const float* __restrict__ b2, float* __restrict__ out, int N){
  __shared__ float sn[4][128];
  const int t = threadIdx.x & 63, wv = threadIdx.x >> 6;
  const int node = blockIdx.x * 4 + wv;
  float h0 = 0.f, h1 = 0.f;
  if (node < N){ h0 = h[(size_t)node * 128 + t]; h1 = h[(size_t)node * 128 + 64 + t]; }
  float mu = wsum64(h0 + h1) * (1.f / 128.f);
  float d0 = h0 - mu, d1 = h1 - mu;
  float var = wsum64(d0 * d0 + d1 * d1) * (1.f / 128.f);
  float rstd = rsqrtf(var + LN_EPS);
  sn[wv][t]      = d0 * rstd * g[t]      + b[t];
  sn[wv][t + 64] = d1 * rstd * g[t + 64] + b[t + 64];
  __syncthreads();
  float a = b1[t];
  #pragma unroll
  for (int k4 = 0; k4 < 32; k4++){
    float4 v = *(const float4*)&sn[wv][k4 * 4];
    a = fmaf(v.x, w1[(k4 * 4 + 0) * 64 + t], a);
    a = fmaf(v.y, w1[(k4 * 4 + 1) * 64 + t], a);
    a = fmaf(v.z, w1[(k4 * 4 + 2) * 64 + t], a);
    a = fmaf(v.w, w1[(k4 * 4 + 3) * 64 + t], a);
  }
  a = fmaxf(a, 0.f);
  float p0 = a * w2[t * 3 + 0], p1 = a * w2[t * 3 + 1], p2 = a * w2[t * 3 + 2];
  p0 = wsum64(p0); p1 = wsum64(p1); p2 = wsum64(p2);
  if (node < N && t == 0){
    out[(size_t)node * 3 + 0] = p0 + b2[0];
    out[(size_t)node * 3 + 1] = p1 + b2[1];
    out[(size_t)node * 3 + 2] = p2 + b2[2];
  }
}

extern "C" void kernel_launch(void* const* d_in, const int* in_sizes, int n_in,
                              void* d_out, int out_size, void* d_ws, size_t ws_size,
                              hipStream_t stream){
  const float* x    = (const float*)d_in[0];
  const int*   ei   = (const int*)d_in[1];
  const float* ea   = (const float*)d_in[2];
  const float* in_w = (const float*)d_in[3];
  const float* in_b = (const float*)d_in[4];
  const float* Wl   = (const float*)d_in[5];
  const float* bl   = (const float*)d_in[6];
  const float* Wr   = (const float*)d_in[7];
  const float* br   = (const float*)d_in[8];
  const float* We   = (const float*)d_in[9];
  const float* att  = (const float*)d_in[10];
  const float* cb   = (const float*)d_in[11];
  const float* lng  = (const float*)d_in[12];
  const float* lnb  = (const float*)d_in[13];
  const float* h1w  = (const float*)d_in[14];
  const float* h1b  = (const float*)d_in[15];
  const float* h2w  = (const float*)d_in[16];
  const float* h2b  = (const float*)d_in[17];
  float* out = (float*)d_out;

  int N = in_sizes[0] / 128;
  int E = in_sizes[1] / 2;
  const int* src = ei;
  const int* dst = ei + E;

  char* w = (char*)d_ws;
  size_t off = 0;
  auto alloc = [&](size_t bytes) -> char* {
    char* p = w + off;
    off = (off + bytes + 255) & ~(size_t)255;
    return p;
  };
  int*   deg   = (int*)alloc((size_t)N * 4);
  int*   cnt   = (int*)alloc((size_t)N * 4);
  int*   ptr   = (int*)alloc((size_t)(N + 1) * 4);
  int*   bsum  = (int*)alloc(256 * 4);
  int*   sx    = (int*)alloc((size_t)E * 4);
  float* cea   = (float*)alloc((size_t)E * 16 * 4);
  unsigned short* xb    = (unsigned short*)alloc((size_t)N * 128 * 2);  // layer-0 gat bf16 out
  unsigned short* hb_in = (unsigned short*)alloc((size_t)N * 128 * 2);
  unsigned short* Bp    = (unsigned short*)alloc((size_t)5 * 16384 * 2);
  float* hf    = (float*)alloc((size_t)N * 128 * 4);
  float* xlb   = (float*)alloc((size_t)N * 128 * 4);
  float* xrb   = (float*)alloc((size_t)N * 128 * 4);

  int nb = (N + 255) / 256;
  hipMemsetAsync(deg, 0, (size_t)N * 4, stream);
  hipMemsetAsync(cnt, 0, (size_t)N * 4, stream);
  k_count<<<(E + 255) / 256, 256, 0, stream>>>(dst, deg, E);
  k_scan_blk<<<nb, 256, 0, stream>>>(deg, ptr, bsum, N);
  k_scan_top<<<1, 256, 0, stream>>>(bsum, nb);
  k_scan_add<<<nb, 256, 0, stream>>>(ptr, bsum, N, E);
  k_fill<<<(E + 255) / 256, 256, 0, stream>>>(dst, src, cnt, ptr, ea, cea, sx, E);

  long n4 = (long)N * 128;
  k_cvt<<<(int)((n4 / 4 + 255) / 256), 256, 0, stream>>>(x, xb, n4);
  k_pack<<<(5 * 2048 + 255) / 256, 256, 0, stream>>>(in_w, Wl, Wl + 16384, Wr, Wr + 16384, Bp);

  int gblocks = (N + 63) / 64;
  // in-proj: h = x @ in_w + in_b  (bf16 out)
  k_mm<<<gblocks, 256, 0, stream>>>(xb, Bp, in_b, hb_in, N);
  for (int l = 0; l < 2; l++){
    const unsigned short* Ain = (l == 0) ? hb_in : xb;  // layer-0 gat writes bf16 into xb
    k_mm_lr<<<gblocks, 256, 0, stream>>>(Ain, Bp + (size_t)(1 + l) * 16384,
                                         Bp + (size_t)(3 + l) * 16384,
                                         bl + l * 128, br + l * 128, xlb, xrb, N);
    k_gat<<<(N + 3) / 4, 256, 0, stream>>>(xlb, xrb, cea, sx, ptr,
                                           We + l * 2048, att + l * 128, cb + l * 128,
                                           hf, xb, N, E, (l == 1) ? 1 : 0, (l == 0) ? 1 : 0);
  }
  k_head<<<(N + 3) / 4, 256, 0, stream>>>(hf, lng, lnb, h1w, h1b, h2w, h2b, out, N);
}